// Round 1
// baseline (1568.414 us; speedup 1.0000x reference)
//
#include <hip/hip_runtime.h>
#include <cstddef>

// Problem constants
#define MROWS 16384          // B*N = 4*4096
#define NSEQ  4096
#define SELU_SCALE 1.0507009873554805f
#define SELU_ALPHA 1.6732632423543772f

__device__ __forceinline__ float selu_f(float x) {
    return x > 0.f ? SELU_SCALE * x : SELU_SCALE * SELU_ALPHA * (__expf(x) - 1.f);
}

// ---------------------------------------------------------------------------
// encode: enc[row, 0:11] = selu(onehot(id)) ; enc[row, 11:25] = selu(props) ;
//         enc[row, 25:32] = 0   (stride 32, zero-padded)
// ---------------------------------------------------------------------------
__global__ void encode_kernel(const float* __restrict__ X, float* __restrict__ enc) {
    int idx = blockIdx.x * 256 + threadIdx.x;
    if (idx >= MROWS * 32) return;
    int row = idx >> 5, col = idx & 31;
    float v;
    if (col < 11) {
        int id = (int)X[(size_t)row * 15];
        v = (id == col) ? (SELU_SCALE * 1.0f) : 0.f;   // selu(1)=scale, selu(0)=0
    } else if (col < 25) {
        v = selu_f(X[(size_t)row * 15 + 1 + (col - 11)]);
    } else {
        v = 0.f;
    }
    enc[idx] = v;
}

// ---------------------------------------------------------------------------
// Generic GEMM: C[M,N] = act(A[M,K] @ W[K,N] + bias), A lda-strided, M=16384.
// 64x64 tile, BK=16, 256 threads, 4x4 per thread.
// A-tile reads may run past K up to lda (or spill into the next row for
// lda==K): values there are finite and multiplied by zeroed W rows.
// ---------------------------------------------------------------------------
template <int ACT>
__global__ __launch_bounds__(256) void gemm_bias_act(
    const float* __restrict__ A, int lda,
    const float* __restrict__ W, const float* __restrict__ bias,
    float* __restrict__ C, int ldc, int N, int K)
{
    __shared__ float As[16][64];
    __shared__ float Ws[16][64];

    int tid = threadIdx.x;
    int tx = tid & 15, ty = tid >> 4;
    int row0 = blockIdx.y * 64;
    int col0 = blockIdx.x * 64;

    float acc[4][4];
#pragma unroll
    for (int i = 0; i < 4; ++i)
#pragma unroll
        for (int j = 0; j < 4; ++j) acc[i][j] = 0.f;

    for (int k0 = 0; k0 < K; k0 += 16) {
        // A tile: one float4 per thread (64 rows x 16 k)
        {
            int r = tid >> 2;
            int k4 = (tid & 3) << 2;
            const float* ap = A + (size_t)(row0 + r) * lda + k0 + k4;
            float4 v = *(const float4*)ap;
            As[k4 + 0][r] = v.x;
            As[k4 + 1][r] = v.y;
            As[k4 + 2][r] = v.z;
            As[k4 + 3][r] = v.w;
        }
        // W tile: bounds-checked
        {
            int kk = tid >> 4;
            int n4 = (tid & 15) << 2;
            int gk = k0 + kk;
            int gc = col0 + n4;
            float4 v = make_float4(0.f, 0.f, 0.f, 0.f);
            if (gk < K) {
                const float* wp = W + (size_t)gk * N + gc;
                if (gc + 3 < N) {
                    v = *(const float4*)wp;
                } else {
                    if (gc + 0 < N) v.x = wp[0];
                    if (gc + 1 < N) v.y = wp[1];
                    if (gc + 2 < N) v.z = wp[2];
                    if (gc + 3 < N) v.w = wp[3];
                }
            }
            *(float4*)&Ws[kk][n4] = v;
        }
        __syncthreads();

#pragma unroll
        for (int kk = 0; kk < 16; ++kk) {
            float4 av = *(const float4*)&As[kk][ty << 2];
            float4 wv = *(const float4*)&Ws[kk][tx << 2];
            float a[4] = {av.x, av.y, av.z, av.w};
            float w[4] = {wv.x, wv.y, wv.z, wv.w};
#pragma unroll
            for (int i = 0; i < 4; ++i)
#pragma unroll
                for (int j = 0; j < 4; ++j) acc[i][j] += a[i] * w[j];
        }
        __syncthreads();
    }

#pragma unroll
    for (int i = 0; i < 4; ++i) {
        int row = row0 + (ty << 2) + i;
#pragma unroll
        for (int j = 0; j < 4; ++j) {
            int col = col0 + (tx << 2) + j;
            if (col < N) {
                float v = acc[i][j] + (bias ? bias[col] : 0.f);
                if (ACT == 1) v = selu_f(v);
                C[(size_t)row * ldc + col] = v;
            }
        }
    }
}

// ---------------------------------------------------------------------------
// Fused adjacency * (x @ W_conv):
// out[b,i,:] = selu( sum_m exp(-4*sqrt(clip(|c1_i|^2 - 2 c1_i.c2_m + |c2_m|^2,
//                                           1e-12,1e12))) * xw[b,m,:] + bconv )
// Block: 32 rows x 256 cols for one batch; stream m in chunks of 32.
// xw and out are stride-264 buffers (cols 0..255 used).
// ---------------------------------------------------------------------------
__global__ __launch_bounds__(256) void adj_conv_kernel(
    const float* __restrict__ c1, const float* __restrict__ c2,
    const float* __restrict__ xw, const float* __restrict__ bconv,
    float* __restrict__ out)
{
    __shared__ float c2s[32][32];
    __shared__ float xws[32][256];
    __shared__ float wT[32][32];   // wT[j][r] = adj^4 value for (row r, m-chunk col j)

    int tid = threadIdx.x;
    int b = blockIdx.y;
    int i0 = blockIdx.x << 5;
    size_t base = (size_t)b * NSEQ;

    // cache this thread's c1 row (r = tid&31) in registers + its norm
    int r = tid & 31;
    float c1r[32];
    float na = 0.f;
    {
        const float* p = c1 + (base + i0 + r) * 32;
#pragma unroll
        for (int k = 0; k < 32; k += 4) {
            float4 v = *(const float4*)(p + k);
            c1r[k] = v.x; c1r[k + 1] = v.y; c1r[k + 2] = v.z; c1r[k + 3] = v.w;
            na += v.x * v.x + v.y * v.y + v.z * v.z + v.w * v.w;
        }
    }

    int ry = (tid >> 5) << 2;   // accumulation rows base (0..28)
    int cx = (tid & 31) << 3;   // accumulation cols base (0..248)
    float acc[4][8];
#pragma unroll
    for (int i = 0; i < 4; ++i)
#pragma unroll
        for (int j = 0; j < 8; ++j) acc[i][j] = 0.f;

    int jg = tid >> 5;          // 0..7

    for (int m0 = 0; m0 < NSEQ; m0 += 32) {
        // stage c2 chunk [32][32]
        {
            int j = tid >> 3, k4 = (tid & 7) << 2;
            *(float4*)&c2s[j][k4] = *(const float4*)(c2 + (base + m0 + j) * 32 + k4);
        }
        // stage xw chunk [32][256]
#pragma unroll
        for (int t = 0; t < 8; ++t) {
            int slot = (t << 8) + tid;
            int row = slot >> 6, c4 = (slot & 63) << 2;
            *(float4*)&xws[row][c4] =
                *(const float4*)(xw + (base + m0 + row) * 264 + c4);
        }
        __syncthreads();

        // distances -> wT
#pragma unroll
        for (int l = 0; l < 4; ++l) {
            int j = (l << 3) + jg;
            float dot = 0.f, nb = 0.f;
#pragma unroll
            for (int k = 0; k < 32; k += 4) {
                float4 v = *(const float4*)&c2s[j][k];
                dot += c1r[k] * v.x + c1r[k + 1] * v.y + c1r[k + 2] * v.z + c1r[k + 3] * v.w;
                nb += v.x * v.x + v.y * v.y + v.z * v.z + v.w * v.w;
            }
            float d = na - 2.f * dot + nb;
            d = fminf(fmaxf(d, 1e-12f), 1e12f);
            wT[j][r] = __expf(-4.f * sqrtf(d));
        }
        __syncthreads();

        // acc += wT^T @ xws
#pragma unroll 8
        for (int m = 0; m < 32; ++m) {
            float4 wv = *(const float4*)&wT[m][ry];
            float4 x0 = *(const float4*)&xws[m][cx];
            float4 x1 = *(const float4*)&xws[m][cx + 4];
            float wa[4] = {wv.x, wv.y, wv.z, wv.w};
            float xa[8] = {x0.x, x0.y, x0.z, x0.w, x1.x, x1.y, x1.z, x1.w};
#pragma unroll
            for (int i = 0; i < 4; ++i)
#pragma unroll
                for (int j = 0; j < 8; ++j) acc[i][j] += wa[i] * xa[j];
        }
        __syncthreads();
    }

    // epilogue: + bconv, selu, store to out (stride 264, cols 0..255)
#pragma unroll
    for (int i = 0; i < 4; ++i) {
        size_t orow = (base + i0 + ry + i) * 264;
        float4 o0, o1;
        o0.x = selu_f(acc[i][0] + bconv[cx + 0]);
        o0.y = selu_f(acc[i][1] + bconv[cx + 1]);
        o0.z = selu_f(acc[i][2] + bconv[cx + 2]);
        o0.w = selu_f(acc[i][3] + bconv[cx + 3]);
        o1.x = selu_f(acc[i][4] + bconv[cx + 4]);
        o1.y = selu_f(acc[i][5] + bconv[cx + 5]);
        o1.z = selu_f(acc[i][6] + bconv[cx + 6]);
        o1.w = selu_f(acc[i][7] + bconv[cx + 7]);
        *(float4*)&out[orow + cx] = o0;
        *(float4*)&out[orow + cx + 4] = o1;
    }
}

// append selu(id_logits) into cols 256..263 of xb buffer (stride 264)
__global__ void append_kernel(const float* __restrict__ idlog, float* __restrict__ xb) {
    int idx = blockIdx.x * 256 + threadIdx.x;
    if (idx >= MROWS * 8) return;
    int row = idx >> 3, c = idx & 7;
    xb[(size_t)row * 264 + 256 + c] = selu_f(idlog[idx]);
}

// final assembly: out[row, 0:8]=id_logits, [8:11]=X[2:5]+corr, [11:13]=charge
__global__ void assemble_kernel(const float* __restrict__ X,
                                const float* __restrict__ idlog,
                                const float* __restrict__ corr,
                                const float* __restrict__ ochv,
                                float* __restrict__ out) {
    int row = blockIdx.x * 256 + threadIdx.x;
    if (row >= MROWS) return;
    const float* xp = X + (size_t)row * 15;
    float* op = out + (size_t)row * 13;
#pragma unroll
    for (int c = 0; c < 8; ++c) op[c] = idlog[(size_t)row * 8 + c];
    op[8] = xp[2] + corr[(size_t)row * 4 + 0];
    op[9] = xp[3] + corr[(size_t)row * 4 + 1];
    op[10] = xp[4] + corr[(size_t)row * 4 + 2];
    op[11] = ochv[(size_t)row * 2 + 0];
    op[12] = ochv[(size_t)row * 2 + 1];
}

static inline void run_gemm(int act, const float* A, int lda, const float* W,
                            const float* bias, float* C, int ldc, int N, int K,
                            hipStream_t s) {
    dim3 g((N + 63) / 64, MROWS / 64), b(256);
    if (act)
        gemm_bias_act<1><<<g, b, 0, s>>>(A, lda, W, bias, C, ldc, N, K);
    else
        gemm_bias_act<0><<<g, b, 0, s>>>(A, lda, W, bias, C, ldc, N, K);
}

extern "C" void kernel_launch(void* const* d_in, const int* in_sizes, int n_in,
                              void* d_out, int out_size, void* d_ws, size_t ws_size,
                              hipStream_t stream) {
    (void)in_sizes; (void)n_in; (void)out_size; (void)ws_size;

    const float* X = (const float*)d_in[0];
    // weights/biases in dict order
    const float* W_dc1 = (const float*)d_in[1];  const float* b_dc1 = (const float*)d_in[2];
    const float* W_dc21 = (const float*)d_in[3]; const float* b_dc21 = (const float*)d_in[4];
    const float* W_dc22 = (const float*)d_in[5]; const float* b_dc22 = (const float*)d_in[6];
    const float* W_in1 = (const float*)d_in[7];  const float* b_in1 = (const float*)d_in[8];
    const float* W_in2 = (const float*)d_in[9];  const float* b_in2 = (const float*)d_in[10];
    const float* W_in3 = (const float*)d_in[11]; const float* b_in3 = (const float*)d_in[12];
    const float* W_conv = (const float*)d_in[13]; const float* b_conv = (const float*)d_in[14];
    const float* W_id1 = (const float*)d_in[15]; const float* b_id1 = (const float*)d_in[16];
    const float* W_id2 = (const float*)d_in[17]; const float* b_id2 = (const float*)d_in[18];
    const float* W_id3 = (const float*)d_in[19]; const float* b_id3 = (const float*)d_in[20];
    const float* W_oid = (const float*)d_in[21]; const float* b_oid = (const float*)d_in[22];
    const float* W_och = (const float*)d_in[23]; const float* b_och = (const float*)d_in[24];
    const float* W_m1 = (const float*)d_in[25];  const float* b_m1 = (const float*)d_in[26];
    const float* W_m2 = (const float*)d_in[27];  const float* b_m2 = (const float*)d_in[28];
    const float* W_m3 = (const float*)d_in[29];  const float* b_m3 = (const float*)d_in[30];
    const float* W_om = (const float*)d_in[31];  const float* b_om = (const float*)d_in[32];

    float* out = (float*)d_out;

    // workspace layout (floats); big stride-264 buffers first so tail
    // over-reads (K=264 A-tiles) land in allocated space.
    const size_t M = MROWS;
    float* A = (float*)d_ws;            // M*264
    float* Bb = A + M * 264;            // M*264
    float* Cc = Bb + M * 264;           // M*264
    float* enc = Cc + M * 264;          // M*32
    float* c1 = enc + M * 32;           // M*32
    float* c2 = c1 + M * 32;            // M*32
    float* idlog = c2 + M * 32;         // M*8
    float* ochv = idlog + M * 8;        // M*2
    float* corr = ochv + M * 2;         // M*4

    // 1. encoding
    encode_kernel<<<(M * 32 + 255) / 256, 256, 0, stream>>>(X, enc);

    // 2. distance-coordinate branch
    run_gemm(1, enc, 32, W_dc1, b_dc1, A, 264, 256, 25, stream);      // h = A
    run_gemm(0, A, 264, W_dc21, b_dc21, c1, 32, 32, 256, stream);
    run_gemm(0, A, 264, W_dc22, b_dc22, c2, 32, 32, 256, stream);

    // 3. node MLP
    run_gemm(1, enc, 32, W_in1, b_in1, Bb, 264, 256, 25, stream);     // x1 = B
    run_gemm(1, Bb, 264, W_in2, b_in2, Cc, 264, 256, 256, stream);    // x2 = C
    run_gemm(1, Cc, 264, W_in3, b_in3, Bb, 264, 256, 256, stream);    // x3 = B
    run_gemm(0, Bb, 264, W_conv, nullptr, Cc, 264, 256, 256, stream); // xw = C

    // 4. fused adjacency conv: xc = A (cols 0..255)
    {
        dim3 g(NSEQ / 32, 4), b(256);
        adj_conv_kernel<<<g, b, 0, stream>>>(c1, c2, Cc, b_conv, A);
    }

    // 5. id head
    run_gemm(1, A, 264, W_id1, b_id1, Bb, 264, 256, 256, stream);     // a1 = B
    run_gemm(1, Bb, 264, W_id2, b_id2, Cc, 264, 256, 256, stream);    // a2 = C
    run_gemm(1, Cc, 264, W_id3, b_id3, Bb, 264, 256, 256, stream);    // a3 = B
    run_gemm(0, Bb, 264, W_oid, b_oid, idlog, 8, 8, 256, stream);
    run_gemm(0, Bb, 264, W_och, b_och, ochv, 2, 2, 256, stream);

    // 6. momentum head: xb = [xc | selu(idlog)] built in place in A
    append_kernel<<<(M * 8 + 255) / 256, 256, 0, stream>>>(idlog, A);
    run_gemm(1, A, 264, W_m1, b_m1, Cc, 264, 264, 264, stream);       // bb1 = C
    run_gemm(1, Cc, 264, W_m2, b_m2, Bb, 264, 256, 264, stream);      // bb2 = B
    run_gemm(1, Bb, 264, W_m3, b_m3, Cc, 264, 256, 256, stream);      // bb3 = C
    run_gemm(0, Cc, 264, W_om, b_om, corr, 4, 3, 256, stream);

    // 7. assemble output [B,N,13]
    assemble_kernel<<<(M + 255) / 256, 256, 0, stream>>>(X, idlog, corr, ochv, out);
}

// Round 2
// 450.080 us; speedup vs baseline: 3.4847x; 3.4847x over previous
//
#include <hip/hip_runtime.h>
#include <cstddef>
#include <cstdint>

#define MROWS 16384          // B*N = 4*4096
#define NSEQ  4096
#define SELU_SCALE  1.0507009873554805f
#define SELU_ASCALE 1.7580993408473766f   // scale*alpha

typedef short bf16x8 __attribute__((ext_vector_type(8)));
typedef float f32x4  __attribute__((ext_vector_type(4)));

__device__ __forceinline__ float selu_f(float x) {
    return x > 0.f ? SELU_SCALE * x : SELU_ASCALE * (__expf(x) - 1.f);
}
// fp32 -> bf16 bits, round-to-nearest-even
__device__ __forceinline__ unsigned short f2bf(float x) {
    union { float f; unsigned int u; } v; v.f = x;
    unsigned int r = v.u + 0x7fffu + ((v.u >> 16) & 1u);
    return (unsigned short)(r >> 16);
}

// ---------------------------------------------------------------------------
// encode: enc[row,0:11]=selu(onehot), [11:25]=selu(props), [25:32]=0  (bf16)
// ---------------------------------------------------------------------------
__global__ void encode_kernel(const float* __restrict__ X, unsigned short* __restrict__ enc) {
    int idx = blockIdx.x * 256 + threadIdx.x;
    if (idx >= MROWS * 32) return;
    int row = idx >> 5, col = idx & 31;
    float v = 0.f;
    if (col < 11) {
        int id = (int)X[(size_t)row * 15];
        v = (id == col) ? SELU_SCALE : 0.f;     // selu(1)=scale, selu(0)=0
    } else if (col < 25) {
        v = selu_f(X[(size_t)row * 15 + 1 + (col - 11)]);
    }
    enc[idx] = f2bf(v);
}

// ---------------------------------------------------------------------------
// prep: transpose-convert all weights fp32 [K][N] -> bf16 WT [Nfill][ldw]
// (rows>=N or k>=K zero-filled), plus concat bias vectors.
// ---------------------------------------------------------------------------
struct PrepEnt { const float* W; unsigned short* WT; int N, K, Nfill, ldw; };
struct PrepArgs {
    PrepEnt e[16];
    const float *b21, *b22, *boid, *boch;
    float *bc12, *boo;
};
__global__ void prep_kernel(PrepArgs pa) {
    if (blockIdx.y < 16) {
        PrepEnt E = pa.e[blockIdx.y];
        int idx = blockIdx.x * 256 + threadIdx.x;
        if (idx < E.Nfill * E.ldw) {
            int n = idx / E.ldw, k = idx - n * E.ldw;
            float v = (n < E.N && k < E.K) ? E.W[(size_t)k * E.N + n] : 0.f;
            E.WT[idx] = f2bf(v);
        }
    } else if (blockIdx.x == 0) {
        int t = threadIdx.x;
        if (t < 32) pa.bc12[t] = pa.b21[t];
        else if (t < 64) pa.bc12[t] = pa.b22[t - 32];
        else if (t < 128) {
            int j = t - 64;
            pa.boo[j] = j < 8 ? pa.boid[j] : (j < 10 ? pa.boch[j - 8] : 0.f);
        }
    }
}

// ---------------------------------------------------------------------------
// bf16 MFMA GEMM: C[M,N] = act(A[M,K]bf16 @ WT^T + bias)
// block tile 128x64, 4 waves (2x2), 16x16x32 MFMA, BK=32.
// A: [M][lda] bf16 (lda mult of 16);  WT: [>=ceil64(N)][ldw] bf16 (zero-padded)
// out: fp32 or bf16, ldc-strided, col<N bounds-checked.
// ---------------------------------------------------------------------------
template <int OUTF32, int ACT>
__global__ __launch_bounds__(256) void gemm_mfma(
    const unsigned short* __restrict__ A, int lda,
    const unsigned short* __restrict__ WT, int ldw,
    const float* __restrict__ bias,
    void* __restrict__ Cp, int ldc, int N, int K)
{
    __shared__ unsigned short As[128][40];   // +16B pad rows: 2-way banks = free
    __shared__ unsigned short Ws[64][40];

    int tid = threadIdx.x;
    int wv = tid >> 6, ln = tid & 63, quad = ln >> 4, l15 = ln & 15;
    int row0 = blockIdx.y * 128, col0 = blockIdx.x * 64;
    int wr = (wv & 1) * 64, wc = (wv >> 1) * 32;

    f32x4 acc[4][2];
#pragma unroll
    for (int i = 0; i < 4; ++i)
#pragma unroll
        for (int j = 0; j < 2; ++j) acc[i][j] = (f32x4){0.f, 0.f, 0.f, 0.f};

    int ar = tid >> 1, ak = (tid & 1) * 16;   // A stage: 128 rows x 32 k
    int wn = tid >> 2, wk = (tid & 3) * 8;    // W stage: 64 rows x 32 k

    for (int k0 = 0; k0 < K; k0 += 32) {
        const unsigned short* ap = A + (size_t)(row0 + ar) * lda + k0 + ak;
        uint4 av0 = *(const uint4*)ap;
        uint4 av1 = *(const uint4*)(ap + 8);
        uint4 wv0 = *(const uint4*)(WT + (size_t)(col0 + wn) * ldw + k0 + wk);
        *(uint4*)&As[ar][ak]     = av0;
        *(uint4*)&As[ar][ak + 8] = av1;
        *(uint4*)&Ws[wn][wk]     = wv0;
        __syncthreads();

        bf16x8 af[4], bfr[2];
#pragma unroll
        for (int mt = 0; mt < 4; ++mt)
            af[mt] = *(const bf16x8*)&As[wr + mt * 16 + l15][quad * 8];
#pragma unroll
        for (int nt = 0; nt < 2; ++nt)
            bfr[nt] = *(const bf16x8*)&Ws[wc + nt * 16 + l15][quad * 8];
#pragma unroll
        for (int mt = 0; mt < 4; ++mt)
#pragma unroll
            for (int nt = 0; nt < 2; ++nt)
                acc[mt][nt] = __builtin_amdgcn_mfma_f32_16x16x32_bf16(
                    af[mt], bfr[nt], acc[mt][nt], 0, 0, 0);
        __syncthreads();
    }

#pragma unroll
    for (int mt = 0; mt < 4; ++mt) {
#pragma unroll
        for (int nt = 0; nt < 2; ++nt) {
            int col = col0 + wc + nt * 16 + l15;
            if (col < N) {
                float bv = bias ? bias[col] : 0.f;
#pragma unroll
                for (int r = 0; r < 4; ++r) {
                    int row = row0 + wr + mt * 16 + quad * 4 + r;
                    float v = acc[mt][nt][r] + bv;
                    if (ACT) v = selu_f(v);
                    if (OUTF32) ((float*)Cp)[(size_t)row * ldc + col] = v;
                    else ((unsigned short*)Cp)[(size_t)row * ldc + col] = f2bf(v);
                }
            }
        }
    }
}

// ---------------------------------------------------------------------------
// norms + bf16 split of c12 fp32 [M][64]: c1b/c2b bf16 [M][32], n1/n2 fp32 [M]
// ---------------------------------------------------------------------------
__global__ void norm_kernel(const float* __restrict__ c12,
                            unsigned short* __restrict__ c1b, unsigned short* __restrict__ c2b,
                            float* __restrict__ n1, float* __restrict__ n2) {
    int row = blockIdx.x * 256 + threadIdx.x;
    if (row >= MROWS) return;
    const float* p = c12 + (size_t)row * 64;
    float s1 = 0.f, s2 = 0.f;
    unsigned int o1[16], o2[16];
#pragma unroll
    for (int k = 0; k < 32; k += 2) {
        float a0 = p[k], a1 = p[k + 1];
        s1 += a0 * a0 + a1 * a1;
        o1[k >> 1] = (unsigned)f2bf(a0) | ((unsigned)f2bf(a1) << 16);
        float b0 = p[32 + k], b1 = p[33 + k];
        s2 += b0 * b0 + b1 * b1;
        o2[k >> 1] = (unsigned)f2bf(b0) | ((unsigned)f2bf(b1) << 16);
    }
    uint4* d1 = (uint4*)(c1b + (size_t)row * 32);
    uint4* d2 = (uint4*)(c2b + (size_t)row * 32);
#pragma unroll
    for (int j = 0; j < 4; ++j) {
        d1[j] = make_uint4(o1[4 * j], o1[4 * j + 1], o1[4 * j + 2], o1[4 * j + 3]);
        d2[j] = make_uint4(o2[4 * j], o2[4 * j + 1], o2[4 * j + 2], o2[4 * j + 3]);
    }
    n1[row] = s1;
    n2[row] = s2;
}

// ---------------------------------------------------------------------------
// transpose xw bf16 [M][288] -> blocked xwTb [b][chunk=128][256 h][32 m] bf16
// ---------------------------------------------------------------------------
__global__ __launch_bounds__(256) void txw_kernel(const unsigned short* __restrict__ xw,
                                                  unsigned short* __restrict__ xwTb) {
    __shared__ unsigned short ins[32][272];   // 256 + 16 pad
    int tid = threadIdx.x;
    int b = blockIdx.y, ck = blockIdx.x;
    size_t srow = (size_t)b * NSEQ + (size_t)ck * 32;
    {
        int m = tid >> 3, c0 = (tid & 7) * 32;
        const unsigned short* sp = xw + (srow + m) * 288 + c0;
#pragma unroll
        for (int j = 0; j < 4; ++j)
            *(uint4*)&ins[m][c0 + j * 8] = *(const uint4*)(sp + j * 8);
    }
    __syncthreads();
    unsigned short* dst = xwTb + (size_t)(b * 128 + ck) * (256 * 32);
#pragma unroll
    for (int p = 0; p < 4; ++p) {
        int idx = p * 256 + tid;
        int h = idx >> 2, j = idx & 3;
        unsigned int w0 = (unsigned)ins[j * 8 + 0][h] | ((unsigned)ins[j * 8 + 1][h] << 16);
        unsigned int w1 = (unsigned)ins[j * 8 + 2][h] | ((unsigned)ins[j * 8 + 3][h] << 16);
        unsigned int w2 = (unsigned)ins[j * 8 + 4][h] | ((unsigned)ins[j * 8 + 5][h] << 16);
        unsigned int w3 = (unsigned)ins[j * 8 + 6][h] | ((unsigned)ins[j * 8 + 7][h] << 16);
        *(uint4*)(dst + (size_t)idx * 8) = make_uint4(w0, w1, w2, w3);
    }
}

// ---------------------------------------------------------------------------
// fused adjacency conv, all-MFMA:
// per block: 32 i-rows x 256 h, stream m in chunks of 32 (double-buffered).
// dot[i][m] via MFMA (c1,c2 bf16), D = n1-2dot+n2 (fp32), w=exp(-4*sqrt(D))
// -> bf16 A-frags via LDS; O += w @ xwT via MFMA; epilogue +bconv, selu.
// ---------------------------------------------------------------------------
__device__ __forceinline__ void adj_stage(
    unsigned short xws_[256][40], unsigned short c2s_[32][40],
    const unsigned short* __restrict__ xwTb, const unsigned short* __restrict__ c2b,
    int b, int chunk, size_t base, int tid)
{
    const unsigned short* src = xwTb + (size_t)(b * 128 + chunk) * (256 * 32);
#pragma unroll
    for (int p = 0; p < 4; ++p) {
        int idx = p * 256 + tid;
        int h = idx >> 2, j = idx & 3;
        *(uint4*)&xws_[h][j * 8] = *(const uint4*)(src + (size_t)idx * 8);
    }
    if (tid < 128) {
        int r = tid >> 2, kk = (tid & 3) * 8;
        *(uint4*)&c2s_[r][kk] = *(const uint4*)(c2b + (base + chunk * 32 + r) * 32 + kk);
    }
}

__global__ __launch_bounds__(256) void adj_conv_mfma(
    const unsigned short* __restrict__ c1b, const unsigned short* __restrict__ c2b,
    const float* __restrict__ n1, const float* __restrict__ n2,
    const unsigned short* __restrict__ xwTb, const float* __restrict__ bconv,
    unsigned short* __restrict__ xc)
{
    __shared__ unsigned short c1s[32][40];
    __shared__ unsigned short c2s[2][32][40];
    __shared__ unsigned short wls[2][32][40];
    __shared__ unsigned short xws[2][256][40];

    int tid = threadIdx.x, wv = tid >> 6, ln = tid & 63, quad = ln >> 4, l15 = ln & 15;
    int b = blockIdx.y, i0 = blockIdx.x * 32;
    size_t base = (size_t)b * NSEQ;
    int it = wv & 1, mt = wv >> 1;   // this wave's 16x16 dot tile

    if (tid < 128) {
        int r = tid >> 2, kk = (tid & 3) * 8;
        *(uint4*)&c1s[r][kk] = *(const uint4*)(c1b + (base + i0 + r) * 32 + kk);
    }
    float n1r[4];
#pragma unroll
    for (int r = 0; r < 4; ++r)
        n1r[r] = n1[base + i0 + it * 16 + quad * 4 + r];

    f32x4 acc[2][4];
#pragma unroll
    for (int i = 0; i < 2; ++i)
#pragma unroll
        for (int j = 0; j < 4; ++j) acc[i][j] = (f32x4){0.f, 0.f, 0.f, 0.f};

    adj_stage(xws[0], c2s[0], xwTb, c2b, b, 0, base, tid);
    __syncthreads();

    int bufp = 0;
    for (int c = 0; c < 128; ++c) {
        // --- 16x16 dot tile via MFMA (K=32 in one shot) ---
        bf16x8 a1 = *(const bf16x8*)&c1s[it * 16 + l15][quad * 8];
        bf16x8 b1 = *(const bf16x8*)&c2s[bufp][mt * 16 + l15][quad * 8];
        f32x4 dot = (f32x4){0.f, 0.f, 0.f, 0.f};
        dot = __builtin_amdgcn_mfma_f32_16x16x32_bf16(a1, b1, dot, 0, 0, 0);
        float nn2 = n2[base + c * 32 + mt * 16 + l15];
#pragma unroll
        for (int r = 0; r < 4; ++r) {
            float D = n1r[r] - 2.f * dot[r] + nn2;
            D = fminf(fmaxf(D, 1e-12f), 1e12f);
            wls[bufp][it * 16 + quad * 4 + r][mt * 16 + l15] = f2bf(__expf(-4.f * sqrtf(D)));
        }
        __syncthreads();   // wls ready; staged bufs from prev iter stable

        // --- main matmul: O(32i x 64h per wave) += w @ xwT ---
        bf16x8 af[2], bfr[4];
#pragma unroll
        for (int i2 = 0; i2 < 2; ++i2)
            af[i2] = *(const bf16x8*)&wls[bufp][i2 * 16 + l15][quad * 8];
#pragma unroll
        for (int ht = 0; ht < 4; ++ht)
            bfr[ht] = *(const bf16x8*)&xws[bufp][wv * 64 + ht * 16 + l15][quad * 8];
#pragma unroll
        for (int i2 = 0; i2 < 2; ++i2)
#pragma unroll
            for (int ht = 0; ht < 4; ++ht)
                acc[i2][ht] = __builtin_amdgcn_mfma_f32_16x16x32_bf16(
                    af[i2], bfr[ht], acc[i2][ht], 0, 0, 0);

        if (c + 1 < 128)
            adj_stage(xws[bufp ^ 1], c2s[bufp ^ 1], xwTb, c2b, b, c + 1, base, tid);
        __syncthreads();
        bufp ^= 1;
    }

#pragma unroll
    for (int i2 = 0; i2 < 2; ++i2) {
#pragma unroll
        for (int ht = 0; ht < 4; ++ht) {
            int h = wv * 64 + ht * 16 + l15;
            float bv = bconv[h];
#pragma unroll
            for (int r = 0; r < 4; ++r) {
                int irow = i0 + i2 * 16 + quad * 4 + r;
                xc[(base + irow) * 288 + h] = f2bf(selu_f(acc[i2][ht][r] + bv));
            }
        }
    }
}

// append selu(id_logits) into bf16 cols 256..263 of xb (stride 288)
__global__ void append_kernel(const float* __restrict__ oo, unsigned short* __restrict__ xb) {
    int idx = blockIdx.x * 256 + threadIdx.x;
    if (idx >= MROWS * 8) return;
    int row = idx >> 3, c = idx & 7;
    xb[(size_t)row * 288 + 256 + c] = f2bf(selu_f(oo[(size_t)row * 16 + c]));
}

// out[row,0:8]=id_logits, [8:11]=X[2:5]+corr, [11:13]=charge
__global__ void assemble_kernel(const float* __restrict__ X,
                                const float* __restrict__ oo,
                                const float* __restrict__ corr,
                                float* __restrict__ out) {
    int row = blockIdx.x * 256 + threadIdx.x;
    if (row >= MROWS) return;
    const float* xp = X + (size_t)row * 15;
    const float* op_ = oo + (size_t)row * 16;
    float* o = out + (size_t)row * 13;
#pragma unroll
    for (int c = 0; c < 8; ++c) o[c] = op_[c];
    o[8]  = xp[2] + corr[(size_t)row * 4 + 0];
    o[9]  = xp[3] + corr[(size_t)row * 4 + 1];
    o[10] = xp[4] + corr[(size_t)row * 4 + 2];
    o[11] = op_[8];
    o[12] = op_[9];
}

extern "C" void kernel_launch(void* const* d_in, const int* in_sizes, int n_in,
                              void* d_out, int out_size, void* d_ws, size_t ws_size,
                              hipStream_t stream) {
    (void)in_sizes; (void)n_in; (void)out_size; (void)ws_size;

    const float* X = (const float*)d_in[0];
    const float* W_dc1 = (const float*)d_in[1];  const float* b_dc1 = (const float*)d_in[2];
    const float* W_dc21 = (const float*)d_in[3]; const float* b_dc21 = (const float*)d_in[4];
    const float* W_dc22 = (const float*)d_in[5]; const float* b_dc22 = (const float*)d_in[6];
    const float* W_in1 = (const float*)d_in[7];  const float* b_in1 = (const float*)d_in[8];
    const float* W_in2 = (const float*)d_in[9];  const float* b_in2 = (const float*)d_in[10];
    const float* W_in3 = (const float*)d_in[11]; const float* b_in3 = (const float*)d_in[12];
    const float* W_conv = (const float*)d_in[13]; const float* b_conv = (const float*)d_in[14];
    const float* W_id1 = (const float*)d_in[15]; const float* b_id1 = (const float*)d_in[16];
    const float* W_id2 = (const float*)d_in[17]; const float* b_id2 = (const float*)d_in[18];
    const float* W_id3 = (const float*)d_in[19]; const float* b_id3 = (const float*)d_in[20];
    const float* W_oid = (const float*)d_in[21]; const float* b_oid = (const float*)d_in[22];
    const float* W_och = (const float*)d_in[23]; const float* b_och = (const float*)d_in[24];
    const float* W_m1 = (const float*)d_in[25];  const float* b_m1 = (const float*)d_in[26];
    const float* W_m2 = (const float*)d_in[27];  const float* b_m2 = (const float*)d_in[28];
    const float* W_m3 = (const float*)d_in[29];  const float* b_m3 = (const float*)d_in[30];
    const float* W_om = (const float*)d_in[31];  const float* b_om = (const float*)d_in[32];

    const size_t M = MROWS;
    char* pw = (char*)d_ws;
    auto alloc = [&](size_t bytes) -> void* {
        void* r = (void*)pw;
        pw += (bytes + 255) & ~(size_t)255;
        return r;
    };
    unsigned short* Abf = (unsigned short*)alloc(M * 288 * 2);
    unsigned short* Bbf = (unsigned short*)alloc(M * 288 * 2);
    unsigned short* Cbf = (unsigned short*)alloc(M * 288 * 2);
    unsigned short* encb = (unsigned short*)alloc(M * 32 * 2);
    float* c12f = (float*)alloc(M * 64 * 4);
    unsigned short* c1b = (unsigned short*)alloc(M * 32 * 2);
    unsigned short* c2b = (unsigned short*)alloc(M * 32 * 2);
    float* n1 = (float*)alloc(M * 4);
    float* n2 = (float*)alloc(M * 4);
    unsigned short* xwTb = (unsigned short*)alloc((size_t)4 * 128 * 256 * 32 * 2);
    float* oof = (float*)alloc(M * 16 * 4);
    float* corrf = (float*)alloc(M * 4 * 4);
    unsigned short* WTdc1 = (unsigned short*)alloc(256 * 32 * 2);
    unsigned short* WTin1 = (unsigned short*)alloc(256 * 32 * 2);
    unsigned short* WTc12 = (unsigned short*)alloc(64 * 256 * 2);
    unsigned short* WTin2 = (unsigned short*)alloc(256 * 256 * 2);
    unsigned short* WTin3 = (unsigned short*)alloc(256 * 256 * 2);
    unsigned short* WTconv = (unsigned short*)alloc(256 * 256 * 2);
    unsigned short* WTid1 = (unsigned short*)alloc(256 * 256 * 2);
    unsigned short* WTid2 = (unsigned short*)alloc(256 * 256 * 2);
    unsigned short* WTid3 = (unsigned short*)alloc(256 * 256 * 2);
    unsigned short* WTm3 = (unsigned short*)alloc(256 * 256 * 2);
    unsigned short* WToo = (unsigned short*)alloc(64 * 256 * 2);
    unsigned short* WTm1 = (unsigned short*)alloc(320 * 288 * 2);
    unsigned short* WTm2 = (unsigned short*)alloc(256 * 288 * 2);
    unsigned short* WTom = (unsigned short*)alloc(64 * 256 * 2);
    float* bc12 = (float*)alloc(64 * 4);
    float* boo = (float*)alloc(64 * 4);

    // zero pad-columns of the three activation buffers (contiguous)
    hipMemsetAsync(Abf, 0, (size_t)3 * M * 288 * 2, stream);

    // weight prep
    PrepArgs pa;
    pa.e[0]  = {W_dc1,  WTdc1,             256, 25,  256, 32};
    pa.e[1]  = {W_in1,  WTin1,             256, 25,  256, 32};
    pa.e[2]  = {W_dc21, WTc12,             32,  256, 32,  256};
    pa.e[3]  = {W_dc22, WTc12 + 32 * 256,  32,  256, 32,  256};
    pa.e[4]  = {W_in2,  WTin2,             256, 256, 256, 256};
    pa.e[5]  = {W_in3,  WTin3,             256, 256, 256, 256};
    pa.e[6]  = {W_conv, WTconv,            256, 256, 256, 256};
    pa.e[7]  = {W_id1,  WTid1,             256, 256, 256, 256};
    pa.e[8]  = {W_id2,  WTid2,             256, 256, 256, 256};
    pa.e[9]  = {W_id3,  WTid3,             256, 256, 256, 256};
    pa.e[10] = {W_m3,   WTm3,              256, 256, 256, 256};
    pa.e[11] = {W_oid,  WToo,              8,   256, 8,   256};
    pa.e[12] = {W_och,  WToo + 8 * 256,    2,   256, 56,  256};
    pa.e[13] = {W_m1,   WTm1,              264, 264, 320, 288};
    pa.e[14] = {W_m2,   WTm2,              256, 264, 256, 288};
    pa.e[15] = {W_om,   WTom,              3,   256, 64,  256};
    pa.b21 = b_dc21; pa.b22 = b_dc22; pa.boid = b_oid; pa.boch = b_och;
    pa.bc12 = bc12; pa.boo = boo;
    prep_kernel<<<dim3(360, 17), 256, 0, stream>>>(pa);

    encode_kernel<<<(M * 32 + 255) / 256, 256, 0, stream>>>(X, encb);

    auto gemm = [&](int outf32, int act, const unsigned short* A, int lda,
                    const unsigned short* WT, int ldw, const float* bias,
                    void* C, int ldc, int N, int K) {
        dim3 g((N + 63) / 64, MROWS / 128), blk(256);
        if (outf32) {
            if (act) gemm_mfma<1, 1><<<g, blk, 0, stream>>>(A, lda, WT, ldw, bias, C, ldc, N, K);
            else     gemm_mfma<1, 0><<<g, blk, 0, stream>>>(A, lda, WT, ldw, bias, C, ldc, N, K);
        } else {
            if (act) gemm_mfma<0, 1><<<g, blk, 0, stream>>>(A, lda, WT, ldw, bias, C, ldc, N, K);
            else     gemm_mfma<0, 0><<<g, blk, 0, stream>>>(A, lda, WT, ldw, bias, C, ldc, N, K);
        }
    };

    // distance-coordinate + node MLP
    gemm(0, 1, encb, 32,  WTdc1, 32,  b_dc1,  Abf, 288, 256, 32);    // h
    gemm(0, 1, encb, 32,  WTin1, 32,  b_in1,  Bbf, 288, 256, 32);    // x1
    gemm(1, 0, Abf, 288,  WTc12, 256, bc12,   c12f, 64, 64, 256);    // c1|c2
    gemm(0, 1, Bbf, 288,  WTin2, 256, b_in2,  Cbf, 288, 256, 256);   // x2
    gemm(0, 1, Cbf, 288,  WTin3, 256, b_in3,  Bbf, 288, 256, 256);   // x3
    gemm(0, 0, Bbf, 288,  WTconv, 256, nullptr, Cbf, 288, 256, 256); // xw

    norm_kernel<<<(M + 255) / 256, 256, 0, stream>>>(c12f, c1b, c2b, n1, n2);
    txw_kernel<<<dim3(128, 4), 256, 0, stream>>>(Cbf, xwTb);
    adj_conv_mfma<<<dim3(128, 4), 256, 0, stream>>>(c1b, c2b, n1, n2, xwTb, b_conv, Abf); // xc

    // id head
    gemm(0, 1, Abf, 288, WTid1, 256, b_id1, Bbf, 288, 256, 256);
    gemm(0, 1, Bbf, 288, WTid2, 256, b_id2, Cbf, 288, 256, 256);
    gemm(0, 1, Cbf, 288, WTid3, 256, b_id3, Bbf, 288, 256, 256);
    gemm(1, 0, Bbf, 288, WToo, 256, boo, oof, 16, 10, 256);          // idlog|charge

    // momentum head: xb = [xc | selu(idlog)] in Abf (K=288, pad cols zero)
    append_kernel<<<(M * 8 + 255) / 256, 256, 0, stream>>>(oof, Abf);
    gemm(0, 1, Abf, 288, WTm1, 288, b_m1, Cbf, 288, 264, 288);
    gemm(0, 1, Cbf, 288, WTm2, 288, b_m2, Bbf, 288, 256, 288);
    gemm(0, 1, Bbf, 288, WTm3, 256, b_m3, Cbf, 288, 256, 256);
    gemm(1, 0, Cbf, 288, WTom, 256, b_om, corrf, 4, 3, 256);

    assemble_kernel<<<(M + 255) / 256, 256, 0, stream>>>(X, oof, corrf, (float*)d_out);
}

// Round 3
// 406.115 us; speedup vs baseline: 3.8620x; 1.1083x over previous
//
#include <hip/hip_runtime.h>
#include <cstddef>
#include <cstdint>

#define MROWS 16384          // B*N = 4*4096
#define NSEQ  4096
#define SELU_SCALE  1.0507009873554805f
#define SELU_ASCALE 1.7580993408473766f   // scale*alpha

typedef short bf16x8 __attribute__((ext_vector_type(8)));
typedef float f32x4  __attribute__((ext_vector_type(4)));

__device__ __forceinline__ float selu_f(float x) {
    return x > 0.f ? SELU_SCALE * x : SELU_ASCALE * (__expf(x) - 1.f);
}
// fp32 -> bf16 bits, round-to-nearest-even
__device__ __forceinline__ unsigned short f2bf(float x) {
    union { float f; unsigned int u; } v; v.f = x;
    unsigned int r = v.u + 0x7fffu + ((v.u >> 16) & 1u);
    return (unsigned short)(r >> 16);
}

#define GLOAD_LDS(gp, lp) \
    __builtin_amdgcn_global_load_lds((const __attribute__((address_space(1))) void*)(gp), \
                                     (__attribute__((address_space(3))) void*)(lp), 16, 0, 0)

// ---------------------------------------------------------------------------
// encode: enc[row,0:11]=selu(onehot), [11:25]=selu(props), [25:32]=0  (bf16)
// ---------------------------------------------------------------------------
__global__ void encode_kernel(const float* __restrict__ X, unsigned short* __restrict__ enc) {
    int idx = blockIdx.x * 256 + threadIdx.x;
    if (idx >= MROWS * 32) return;
    int row = idx >> 5, col = idx & 31;
    float v = 0.f;
    if (col < 11) {
        int id = (int)X[(size_t)row * 15];
        v = (id == col) ? SELU_SCALE : 0.f;     // selu(1)=scale, selu(0)=0
    } else if (col < 25) {
        v = selu_f(X[(size_t)row * 15 + 1 + (col - 11)]);
    }
    enc[idx] = f2bf(v);
}

// ---------------------------------------------------------------------------
// prep: transpose-convert all weights fp32 [K][N] -> bf16 WT [Nfill][ldw]
// (rows>=N or k>=K zero-filled), plus concat bias vectors.
// ---------------------------------------------------------------------------
struct PrepEnt { const float* W; unsigned short* WT; int N, K, Nfill, ldw; };
struct PrepArgs {
    PrepEnt e[16];
    const float *b21, *b22, *boid, *boch, *bdc1, *bin1;
    float *bc12, *boo, *bcat;
};
__global__ void prep_kernel(PrepArgs pa) {
    if (blockIdx.y < 16) {
        PrepEnt E = pa.e[blockIdx.y];
        int idx = blockIdx.x * 256 + threadIdx.x;
        if (idx < E.Nfill * E.ldw) {
            int n = idx / E.ldw, k = idx - n * E.ldw;
            float v = (n < E.N && k < E.K) ? E.W[(size_t)k * E.N + n] : 0.f;
            E.WT[idx] = f2bf(v);
        }
    } else if (blockIdx.x == 0) {
        int t = threadIdx.x;
        if (t < 32) pa.bc12[t] = pa.b21[t];
        else if (t < 64) pa.bc12[t] = pa.b22[t - 32];
        else if (t < 128) {
            int j = t - 64;
            pa.boo[j] = j < 8 ? pa.boid[j] : (j < 10 ? pa.boch[j - 8] : 0.f);
        }
    } else if (blockIdx.x == 1) {
        pa.bcat[threadIdx.x] = pa.bdc1[threadIdx.x];
    } else if (blockIdx.x == 2) {
        pa.bcat[256 + threadIdx.x] = pa.bin1[threadIdx.x];
    }
}

// ---------------------------------------------------------------------------
// bf16 MFMA GEMM (m97-style): C[M,N] = act(A[M,K]bf16 @ WT^T + bias)
// block tile 128x64, 4 waves (2x2), 16x16x32 MFMA, BK=32.
// Staging via global_load_lds width=16 into unpadded LDS.
// Optional split epilogue: cols >= 256 go to Cp2 (stride 288, col-256).
// ---------------------------------------------------------------------------
template <int OUTF32, int ACT>
__global__ __launch_bounds__(256) void gemm_mfma(
    const unsigned short* __restrict__ A, int lda,
    const unsigned short* __restrict__ WT, int ldw,
    const float* __restrict__ bias,
    void* __restrict__ Cp, int ldc, int N, int K,
    unsigned short* __restrict__ Cp2)
{
    __shared__ unsigned short As[128 * 32];
    __shared__ unsigned short Ws[64 * 32];

    int tid = threadIdx.x;
    int wv = tid >> 6, ln = tid & 63, quad = ln >> 4, l15 = ln & 15;
    int row0 = blockIdx.y * 128, col0 = blockIdx.x * 64;
    int wr = (wv & 1) * 64, wc = (wv >> 1) * 32;

    f32x4 acc[4][2];
#pragma unroll
    for (int i = 0; i < 4; ++i)
#pragma unroll
        for (int j = 0; j < 2; ++j) acc[i][j] = (f32x4){0.f, 0.f, 0.f, 0.f};

    // per-lane global addresses for direct-to-LDS staging (lane i -> lds+16B*i)
    const unsigned short* ag0 = A + (size_t)(row0 + wv * 32 + (ln >> 2)) * lda + (ln & 3) * 8;
    const unsigned short* ag1 = ag0 + (size_t)16 * lda;
    const unsigned short* wg  = WT + (size_t)(col0 + wv * 16 + (ln >> 2)) * ldw + (ln & 3) * 8;
    unsigned short* al0 = As + wv * 1024;
    unsigned short* al1 = As + wv * 1024 + 512;
    unsigned short* wl  = Ws + wv * 512;

    for (int k0 = 0; k0 < K; k0 += 32) {
        GLOAD_LDS(ag0 + k0, al0);
        GLOAD_LDS(ag1 + k0, al1);
        GLOAD_LDS(wg + k0, wl);
        __syncthreads();

        bf16x8 af[4], bfr[2];
#pragma unroll
        for (int mt = 0; mt < 4; ++mt)
            af[mt] = *(const bf16x8*)&As[(wr + mt * 16 + l15) * 32 + quad * 8];
#pragma unroll
        for (int nt = 0; nt < 2; ++nt)
            bfr[nt] = *(const bf16x8*)&Ws[(wc + nt * 16 + l15) * 32 + quad * 8];
#pragma unroll
        for (int mt = 0; mt < 4; ++mt)
#pragma unroll
            for (int nt = 0; nt < 2; ++nt)
                acc[mt][nt] = __builtin_amdgcn_mfma_f32_16x16x32_bf16(
                    af[mt], bfr[nt], acc[mt][nt], 0, 0, 0);
        __syncthreads();
    }

#pragma unroll
    for (int mt = 0; mt < 4; ++mt) {
#pragma unroll
        for (int nt = 0; nt < 2; ++nt) {
            int col = col0 + wc + nt * 16 + l15;
            if (col < N) {
                float bv = bias ? bias[col] : 0.f;
#pragma unroll
                for (int r = 0; r < 4; ++r) {
                    int row = row0 + wr + mt * 16 + quad * 4 + r;
                    float v = acc[mt][nt][r] + bv;
                    if (ACT) v = selu_f(v);
                    if (OUTF32) {
                        ((float*)Cp)[(size_t)row * ldc + col] = v;
                    } else if (Cp2 && col >= 256) {
                        Cp2[(size_t)row * 288 + (col - 256)] = f2bf(v);
                    } else {
                        ((unsigned short*)Cp)[(size_t)row * ldc + col] = f2bf(v);
                    }
                }
            }
        }
    }
}

// ---------------------------------------------------------------------------
// norms + bf16 split of c12 fp32 [M][64]: c1b/c2b bf16 [M][32], n1/n2 fp32 [M]
// ---------------------------------------------------------------------------
__global__ void norm_kernel(const float* __restrict__ c12,
                            unsigned short* __restrict__ c1b, unsigned short* __restrict__ c2b,
                            float* __restrict__ n1, float* __restrict__ n2) {
    int row = blockIdx.x * 256 + threadIdx.x;
    if (row >= MROWS) return;
    const float* p = c12 + (size_t)row * 64;
    float s1 = 0.f, s2 = 0.f;
    unsigned int o1[16], o2[16];
#pragma unroll
    for (int k = 0; k < 32; k += 2) {
        float a0 = p[k], a1 = p[k + 1];
        s1 += a0 * a0 + a1 * a1;
        o1[k >> 1] = (unsigned)f2bf(a0) | ((unsigned)f2bf(a1) << 16);
        float b0 = p[32 + k], b1 = p[33 + k];
        s2 += b0 * b0 + b1 * b1;
        o2[k >> 1] = (unsigned)f2bf(b0) | ((unsigned)f2bf(b1) << 16);
    }
    uint4* d1 = (uint4*)(c1b + (size_t)row * 32);
    uint4* d2 = (uint4*)(c2b + (size_t)row * 32);
#pragma unroll
    for (int j = 0; j < 4; ++j) {
        d1[j] = make_uint4(o1[4 * j], o1[4 * j + 1], o1[4 * j + 2], o1[4 * j + 3]);
        d2[j] = make_uint4(o2[4 * j], o2[4 * j + 1], o2[4 * j + 2], o2[4 * j + 3]);
    }
    n1[row] = s1;
    n2[row] = s2;
}

// ---------------------------------------------------------------------------
// transpose xw bf16 [M][288] -> blocked xwTb [b][chunk=128][256 h][32 m] bf16
// ---------------------------------------------------------------------------
__global__ __launch_bounds__(256) void txw_kernel(const unsigned short* __restrict__ xw,
                                                  unsigned short* __restrict__ xwTb) {
    __shared__ unsigned short ins[32][272];   // 256 + 16 pad
    int tid = threadIdx.x;
    int b = blockIdx.y, ck = blockIdx.x;
    size_t srow = (size_t)b * NSEQ + (size_t)ck * 32;
    {
        int m = tid >> 3, c0 = (tid & 7) * 32;
        const unsigned short* sp = xw + (srow + m) * 288 + c0;
#pragma unroll
        for (int j = 0; j < 4; ++j)
            *(uint4*)&ins[m][c0 + j * 8] = *(const uint4*)(sp + j * 8);
    }
    __syncthreads();
    unsigned short* dst = xwTb + (size_t)(b * 128 + ck) * (256 * 32);
#pragma unroll
    for (int p = 0; p < 4; ++p) {
        int idx = p * 256 + tid;
        int h = idx >> 2, j = idx & 3;
        unsigned int w0 = (unsigned)ins[j * 8 + 0][h] | ((unsigned)ins[j * 8 + 1][h] << 16);
        unsigned int w1 = (unsigned)ins[j * 8 + 2][h] | ((unsigned)ins[j * 8 + 3][h] << 16);
        unsigned int w2 = (unsigned)ins[j * 8 + 4][h] | ((unsigned)ins[j * 8 + 5][h] << 16);
        unsigned int w3 = (unsigned)ins[j * 8 + 6][h] | ((unsigned)ins[j * 8 + 7][h] << 16);
        *(uint4*)(dst + (size_t)idx * 8) = make_uint4(w0, w1, w2, w3);
    }
}

// ---------------------------------------------------------------------------
// fused adjacency conv v2 — direct-global MFMA fragments, LDS only for the
// exp-weight layout transform (double-buffered, 1 barrier per 64-m chunk).
// Grid: 256 blocks (XCD-swizzled: 2 XCDs per batch), 512 threads (8 waves).
// Block tile: 64 i-rows x 256 h; wave wv: h in [wv*32, wv*32+32).
// Dot duty: wave wv computes w[ it=wv&3 ][ mt = (wv>>2)*2 + {0,1} ] tiles.
// ---------------------------------------------------------------------------
__global__ __launch_bounds__(512) void adj_conv_mfma(
    const unsigned short* __restrict__ c1b, const unsigned short* __restrict__ c2b,
    const float* __restrict__ n1, const float* __restrict__ n2,
    const unsigned short* __restrict__ xwTb, const float* __restrict__ bconv,
    unsigned short* __restrict__ xc)
{
    __shared__ unsigned short wls[2][64][72];

    int tid = threadIdx.x, wv = tid >> 6, ln = tid & 63, quad = ln >> 4, l15 = ln & 15;
    int blk = blockIdx.x;
    int b = (blk >> 1) & 3;                       // XCD pair -> batch
    int itile = ((blk >> 3) << 1) | (blk & 1);    // 0..63
    int i0 = itile * 64;
    size_t base = (size_t)b * NSEQ;

    int it = wv & 3;               // dot i-tile (rows it*16..+15)
    int mtb = (wv >> 2) << 1;      // dot m-tiles mtb, mtb+1

    // fixed A-frag (c1 rows) + n1 quad (C-layout rows)
    bf16x8 c1f = *(const bf16x8*)(c1b + (base + i0 + it * 16 + l15) * 32 + quad * 8);
    float4 n1v = *(const float4*)(n1 + base + i0 + it * 16 + quad * 4);

    const unsigned short* xwb = xwTb + (size_t)b * 128 * 256 * 32;

    f32x4 acc[4][2];
#pragma unroll
    for (int i = 0; i < 4; ++i)
#pragma unroll
        for (int j = 0; j < 2; ++j) acc[i][j] = (f32x4){0.f, 0.f, 0.f, 0.f};

    // prefetch for iter 0
    bf16x8 c2f[2]; float nn2[2];
    bf16x8 bfc[2][2], bfn[2][2];
#pragma unroll
    for (int t = 0; t < 2; ++t) {
        int mt = mtb + t;
        c2f[t] = *(const bf16x8*)(c2b + (base + mt * 16 + l15) * 32 + quad * 8);
        nn2[t] = n2[base + mt * 16 + l15];
    }
#pragma unroll
    for (int ht = 0; ht < 2; ++ht)
#pragma unroll
        for (int ks = 0; ks < 2; ++ks)
            bfc[ht][ks] = *(const bf16x8*)(xwb +
                ((size_t)ks * 256 + wv * 32 + ht * 16 + l15) * 32 + quad * 8);

#pragma unroll 2
    for (int itr = 0; itr < 64; ++itr) {
        int p = itr & 1;
        // ---- dot phase: D -> exp -> wls[p] ----
#pragma unroll
        for (int t = 0; t < 2; ++t) {
            int mt = mtb + t;
            f32x4 dotv = (f32x4){0.f, 0.f, 0.f, 0.f};
            dotv = __builtin_amdgcn_mfma_f32_16x16x32_bf16(c1f, c2f[t], dotv, 0, 0, 0);
            float s = nn2[t];
#pragma unroll
            for (int r = 0; r < 4; ++r) {
                float D = fmaf(-2.f, dotv[r], n1v[r == 0 ? 0 : r] + s);
                D = fmaxf(D, 1e-12f);
                wls[p][it * 16 + quad * 4 + r][mt * 16 + l15] = f2bf(__expf(-4.f * sqrtf(D)));
            }
        }
        __syncthreads();

        // ---- A-frags from wls, prefetch next iter's globals ----
        bf16x8 af[4][2];
#pragma unroll
        for (int mi = 0; mi < 4; ++mi)
#pragma unroll
            for (int ks = 0; ks < 2; ++ks)
                af[mi][ks] = *(const bf16x8*)&wls[p][mi * 16 + l15][ks * 32 + quad * 8];

        if (itr < 63) {
            int m0n = (itr + 1) * 64;
#pragma unroll
            for (int t = 0; t < 2; ++t) {
                int mt = mtb + t;
                c2f[t] = *(const bf16x8*)(c2b + (base + m0n + mt * 16 + l15) * 32 + quad * 8);
                nn2[t] = n2[base + m0n + mt * 16 + l15];
            }
#pragma unroll
            for (int ht = 0; ht < 2; ++ht)
#pragma unroll
                for (int ks = 0; ks < 2; ++ks)
                    bfn[ht][ks] = *(const bf16x8*)(xwb +
                        ((size_t)((itr + 1) * 2 + ks) * 256 + wv * 32 + ht * 16 + l15) * 32 + quad * 8);
        }

        // ---- main MFMAs: acc[i][h] += w[i][m] * xwT[h][m] ----
#pragma unroll
        for (int mi = 0; mi < 4; ++mi)
#pragma unroll
            for (int ht = 0; ht < 2; ++ht)
#pragma unroll
                for (int ks = 0; ks < 2; ++ks)
                    acc[mi][ht] = __builtin_amdgcn_mfma_f32_16x16x32_bf16(
                        af[mi][ks], bfc[ht][ks], acc[mi][ht], 0, 0, 0);
#pragma unroll
        for (int ht = 0; ht < 2; ++ht)
#pragma unroll
            for (int ks = 0; ks < 2; ++ks)
                bfc[ht][ks] = bfn[ht][ks];
    }

    // epilogue: + bconv, selu, store bf16 (stride 288)
#pragma unroll
    for (int mi = 0; mi < 4; ++mi) {
#pragma unroll
        for (int ht = 0; ht < 2; ++ht) {
            int h = wv * 32 + ht * 16 + l15;
            float bv = bconv[h];
#pragma unroll
            for (int r = 0; r < 4; ++r) {
                int irow = i0 + mi * 16 + quad * 4 + r;
                xc[(base + irow) * 288 + h] = f2bf(selu_f(acc[mi][ht][r] + bv));
            }
        }
    }
}

// append selu(id_logits) into bf16 cols 256..263 of xb (stride 288)
__global__ void append_kernel(const float* __restrict__ oo, unsigned short* __restrict__ xb) {
    int idx = blockIdx.x * 256 + threadIdx.x;
    if (idx >= MROWS * 8) return;
    int row = idx >> 3, c = idx & 7;
    xb[(size_t)row * 288 + 256 + c] = f2bf(selu_f(oo[(size_t)row * 16 + c]));
}

// out[row,0:8]=id_logits, [8:11]=X[2:5]+corr, [11:13]=charge
__global__ void assemble_kernel(const float* __restrict__ X,
                                const float* __restrict__ oo,
                                const float* __restrict__ corr,
                                float* __restrict__ out) {
    int row = blockIdx.x * 256 + threadIdx.x;
    if (row >= MROWS) return;
    const float* xp = X + (size_t)row * 15;
    const float* op_ = oo + (size_t)row * 16;
    float* o = out + (size_t)row * 13;
#pragma unroll
    for (int c = 0; c < 8; ++c) o[c] = op_[c];
    o[8]  = xp[2] + corr[(size_t)row * 4 + 0];
    o[9]  = xp[3] + corr[(size_t)row * 4 + 1];
    o[10] = xp[4] + corr[(size_t)row * 4 + 2];
    o[11] = op_[8];
    o[12] = op_[9];
}

extern "C" void kernel_launch(void* const* d_in, const int* in_sizes, int n_in,
                              void* d_out, int out_size, void* d_ws, size_t ws_size,
                              hipStream_t stream) {
    (void)in_sizes; (void)n_in; (void)out_size; (void)ws_size;

    const float* X = (const float*)d_in[0];
    const float* W_dc1 = (const float*)d_in[1];  const float* b_dc1 = (const float*)d_in[2];
    const float* W_dc21 = (const float*)d_in[3]; const float* b_dc21 = (const float*)d_in[4];
    const float* W_dc22 = (const float*)d_in[5]; const float* b_dc22 = (const float*)d_in[6];
    const float* W_in1 = (const float*)d_in[7];  const float* b_in1 = (const float*)d_in[8];
    const float* W_in2 = (const float*)d_in[9];  const float* b_in2 = (const float*)d_in[10];
    const float* W_in3 = (const float*)d_in[11]; const float* b_in3 = (const float*)d_in[12];
    const float* W_conv = (const float*)d_in[13]; const float* b_conv = (const float*)d_in[14];
    const float* W_id1 = (const float*)d_in[15]; const float* b_id1 = (const float*)d_in[16];
    const float* W_id2 = (const float*)d_in[17]; const float* b_id2 = (const float*)d_in[18];
    const float* W_id3 = (const float*)d_in[19]; const float* b_id3 = (const float*)d_in[20];
    const float* W_oid = (const float*)d_in[21]; const float* b_oid = (const float*)d_in[22];
    const float* W_och = (const float*)d_in[23]; const float* b_och = (const float*)d_in[24];
    const float* W_m1 = (const float*)d_in[25];  const float* b_m1 = (const float*)d_in[26];
    const float* W_m2 = (const float*)d_in[27];  const float* b_m2 = (const float*)d_in[28];
    const float* W_m3 = (const float*)d_in[29];  const float* b_m3 = (const float*)d_in[30];
    const float* W_om = (const float*)d_in[31];  const float* b_om = (const float*)d_in[32];

    const size_t M = MROWS;
    char* pw = (char*)d_ws;
    auto alloc = [&](size_t bytes) -> void* {
        void* r = (void*)pw;
        pw += (bytes + 255) & ~(size_t)255;
        return r;
    };
    unsigned short* Abf = (unsigned short*)alloc(M * 288 * 2);
    unsigned short* Bbf = (unsigned short*)alloc(M * 288 * 2);
    unsigned short* Cbf = (unsigned short*)alloc(M * 288 * 2);
    unsigned short* encb = (unsigned short*)alloc(M * 32 * 2);
    float* c12f = (float*)alloc(M * 64 * 4);
    unsigned short* c1b = (unsigned short*)alloc(M * 32 * 2);
    unsigned short* c2b = (unsigned short*)alloc(M * 32 * 2);
    float* n1 = (float*)alloc(M * 4);
    float* n2 = (float*)alloc(M * 4);
    unsigned short* xwTb = (unsigned short*)alloc((size_t)4 * 128 * 256 * 32 * 2);
    float* oof = (float*)alloc(M * 16 * 4);
    float* corrf = (float*)alloc(M * 4 * 4);
    unsigned short* WTd = (unsigned short*)alloc(512 * 32 * 2);     // dc1|in1 concat
    unsigned short* WTc12 = (unsigned short*)alloc(64 * 256 * 2);
    unsigned short* WTin2 = (unsigned short*)alloc(256 * 256 * 2);
    unsigned short* WTin3 = (unsigned short*)alloc(256 * 256 * 2);
    unsigned short* WTconv = (unsigned short*)alloc(256 * 256 * 2);
    unsigned short* WTid1 = (unsigned short*)alloc(256 * 256 * 2);
    unsigned short* WTid2 = (unsigned short*)alloc(256 * 256 * 2);
    unsigned short* WTid3 = (unsigned short*)alloc(256 * 256 * 2);
    unsigned short* WTm3 = (unsigned short*)alloc(256 * 256 * 2);
    unsigned short* WToo = (unsigned short*)alloc(64 * 256 * 2);
    unsigned short* WTm1 = (unsigned short*)alloc(320 * 288 * 2);
    unsigned short* WTm2 = (unsigned short*)alloc(256 * 288 * 2);
    unsigned short* WTom = (unsigned short*)alloc(64 * 256 * 2);
    float* bc12 = (float*)alloc(64 * 4);
    float* boo = (float*)alloc(64 * 4);
    float* bcat = (float*)alloc(512 * 4);

    // zero pad-columns of the three activation buffers (contiguous)
    hipMemsetAsync(Abf, 0, (size_t)3 * M * 288 * 2, stream);

    // weight prep
    PrepArgs pa;
    pa.e[0]  = {W_dc1,  WTd,               256, 25,  256, 32};
    pa.e[1]  = {W_in1,  WTd + 256 * 32,    256, 25,  256, 32};
    pa.e[2]  = {W_dc21, WTc12,             32,  256, 32,  256};
    pa.e[3]  = {W_dc22, WTc12 + 32 * 256,  32,  256, 32,  256};
    pa.e[4]  = {W_in2,  WTin2,             256, 256, 256, 256};
    pa.e[5]  = {W_in3,  WTin3,             256, 256, 256, 256};
    pa.e[6]  = {W_conv, WTconv,            256, 256, 256, 256};
    pa.e[7]  = {W_id1,  WTid1,             256, 256, 256, 256};
    pa.e[8]  = {W_id2,  WTid2,             256, 256, 256, 256};
    pa.e[9]  = {W_id3,  WTid3,             256, 256, 256, 256};
    pa.e[10] = {W_m3,   WTm3,              256, 256, 256, 256};
    pa.e[11] = {W_oid,  WToo,              8,   256, 8,   256};
    pa.e[12] = {W_och,  WToo + 8 * 256,    2,   256, 56,  256};
    pa.e[13] = {W_m1,   WTm1,              264, 264, 320, 288};
    pa.e[14] = {W_m2,   WTm2,              256, 264, 256, 288};
    pa.e[15] = {W_om,   WTom,              3,   256, 64,  256};
    pa.b21 = b_dc21; pa.b22 = b_dc22; pa.boid = b_oid; pa.boch = b_och;
    pa.bdc1 = b_dc1; pa.bin1 = b_in1;
    pa.bc12 = bc12; pa.boo = boo; pa.bcat = bcat;
    prep_kernel<<<dim3(360, 17), 256, 0, stream>>>(pa);

    encode_kernel<<<(M * 32 + 255) / 256, 256, 0, stream>>>(X, encb);

    auto gemm = [&](int outf32, int act, const unsigned short* A, int lda,
                    const unsigned short* WT, int ldw, const float* bias,
                    void* C, int ldc, int N, int K, unsigned short* C2 = nullptr) {
        dim3 g((N + 63) / 64, MROWS / 128), blk(256);
        if (outf32) {
            if (act) gemm_mfma<1, 1><<<g, blk, 0, stream>>>(A, lda, WT, ldw, bias, C, ldc, N, K, C2);
            else     gemm_mfma<1, 0><<<g, blk, 0, stream>>>(A, lda, WT, ldw, bias, C, ldc, N, K, C2);
        } else {
            if (act) gemm_mfma<0, 1><<<g, blk, 0, stream>>>(A, lda, WT, ldw, bias, C, ldc, N, K, C2);
            else     gemm_mfma<0, 0><<<g, blk, 0, stream>>>(A, lda, WT, ldw, bias, C, ldc, N, K, C2);
        }
    };

    // fused dc1+in1: h -> Abf (cols<256), x1 -> Bbf (cols>=256)
    gemm(0, 1, encb, 32, WTd, 32, bcat, Abf, 288, 512, 32, Bbf);
    gemm(1, 0, Abf, 288, WTc12, 256, bc12, c12f, 64, 64, 256);       // c1|c2
    gemm(0, 1, Bbf, 288, WTin2, 256, b_in2, Cbf, 288, 256, 256);     // x2
    gemm(0, 1, Cbf, 288, WTin3, 256, b_in3, Bbf, 288, 256, 256);     // x3
    gemm(0, 0, Bbf, 288, WTconv, 256, nullptr, Cbf, 288, 256, 256);  // xw

    norm_kernel<<<(M + 255) / 256, 256, 0, stream>>>(c12f, c1b, c2b, n1, n2);
    txw_kernel<<<dim3(128, 4), 256, 0, stream>>>(Cbf, xwTb);
    adj_conv_mfma<<<dim3(256), 512, 0, stream>>>(c1b, c2b, n1, n2, xwTb, b_conv, Abf); // xc

    // id head
    gemm(0, 1, Abf, 288, WTid1, 256, b_id1, Bbf, 288, 256, 256);
    gemm(0, 1, Bbf, 288, WTid2, 256, b_id2, Cbf, 288, 256, 256);
    gemm(0, 1, Cbf, 288, WTid3, 256, b_id3, Bbf, 288, 256, 256);
    gemm(1, 0, Bbf, 288, WToo, 256, boo, oof, 16, 10, 256);          // idlog|charge

    // momentum head: xb = [xc | selu(idlog)] in Abf (K=288, pad cols zero)
    append_kernel<<<(M * 8 + 255) / 256, 256, 0, stream>>>(oof, Abf);
    gemm(0, 1, Abf, 288, WTm1, 288, b_m1, Cbf, 288, 264, 288);
    gemm(0, 1, Cbf, 288, WTm2, 288, b_m2, Bbf, 288, 256, 288);
    gemm(0, 1, Bbf, 288, WTm3, 256, b_m3, Cbf, 288, 256, 256);
    gemm(1, 0, Cbf, 288, WTom, 256, b_om, corrf, 4, 3, 256);

    assemble_kernel<<<(M + 255) / 256, 256, 0, stream>>>(X, oof, corrf, (float*)d_out);
}

// Round 4
// 294.804 us; speedup vs baseline: 5.3202x; 1.3776x over previous
//
#include <hip/hip_runtime.h>
#include <cstddef>
#include <cstdint>

#define MROWS 16384          // B*N = 4*4096
#define NSEQ  4096
#define ASTR  296            // LDS activation row stride (shorts): bank-stride 20 -> 2-way (free)
#define SELU_SCALE  1.0507009873554805f
#define SELU_ASCALE 1.7580993408473766f   // scale*alpha

typedef short bf16x8 __attribute__((ext_vector_type(8)));
typedef float f32x4  __attribute__((ext_vector_type(4)));

__device__ __forceinline__ float selu_f(float x) {
    return x > 0.f ? SELU_SCALE * x : SELU_ASCALE * (__expf(x) - 1.f);
}
// fp32 -> bf16 bits, round-to-nearest-even
__device__ __forceinline__ unsigned short f2bf(float x) {
    union { float f; unsigned int u; } v; v.f = x;
    unsigned int r = v.u + 0x7fffu + ((v.u >> 16) & 1u);
    return (unsigned short)(r >> 16);
}
// truncating cvt (for adjacency weights w<=1: bias harmless, saves VALU)
__device__ __forceinline__ unsigned short t2bf(float x) {
    union { float f; unsigned int u; } v; v.f = x;
    return (unsigned short)(v.u >> 16);
}

// ---------------------------------------------------------------------------
// prep: transpose-convert all weights fp32 [K][N] -> bf16 WT [Nfill][ldw]
// ---------------------------------------------------------------------------
struct PrepEnt { const float* W; unsigned short* WT; int N, K, Nfill, ldw; };
struct PrepArgs {
    PrepEnt e[16];
    const float *b21, *b22, *boid, *boch, *bdc1, *bin1;
    float *bc12, *boo, *bcat;
};
__global__ void prep_kernel(PrepArgs pa) {
    if (blockIdx.y < 16) {
        PrepEnt E = pa.e[blockIdx.y];
        int idx = blockIdx.x * 256 + threadIdx.x;
        if (idx < E.Nfill * E.ldw) {
            int n = idx / E.ldw, k = idx - n * E.ldw;
            float v = (n < E.N && k < E.K) ? E.W[(size_t)k * E.N + n] : 0.f;
            E.WT[idx] = f2bf(v);
        }
    } else if (blockIdx.x == 0) {
        int t = threadIdx.x;
        if (t < 32) pa.bc12[t] = pa.b21[t];
        else if (t < 64) pa.bc12[t] = pa.b22[t - 32];
        else if (t < 128) {
            int j = t - 64;
            pa.boo[j] = j < 8 ? pa.boid[j] : (j < 10 ? pa.boch[j - 8] : 0.f);
        }
    } else if (blockIdx.x == 1) {
        pa.bcat[threadIdx.x] = pa.bdc1[threadIdx.x];
    } else if (blockIdx.x == 2) {
        pa.bcat[256 + threadIdx.x] = pa.bin1[threadIdx.x];
    }
}

// ---------------------------------------------------------------------------
// Mega-kernel building blocks: 64-row act tile in LDS (stride ASTR),
// weights streamed as direct global b128 B-frags (L2-hot, reg dbuf).
// ---------------------------------------------------------------------------
template <int NT>
__device__ __forceinline__ void zero_acc(f32x4 (&acc)[4][NT]) {
#pragma unroll
    for (int i = 0; i < 4; ++i)
#pragma unroll
        for (int nt = 0; nt < NT; ++nt) acc[i][nt] = (f32x4){0.f, 0.f, 0.f, 0.f};
}

template <int NT, int K>
__device__ __forceinline__ void compute_tiles(
    f32x4 (&acc)[4][NT],
    const unsigned short* __restrict__ src, int sstr,
    const unsigned short* __restrict__ WT, int ldw,
    int col0, int ln)
{
    int quad = ln >> 4, l15 = ln & 15;
    const unsigned short* wbase = WT + (size_t)(col0 + l15) * ldw + quad * 8;
    bf16x8 bcur[NT];
#pragma unroll
    for (int nt = 0; nt < NT; ++nt)
        bcur[nt] = *(const bf16x8*)(wbase + nt * 16 * ldw);
#pragma unroll
    for (int k0 = 0; k0 < K; k0 += 32) {
        bf16x8 bnxt[NT];
        if (k0 + 32 < K) {
#pragma unroll
            for (int nt = 0; nt < NT; ++nt)
                bnxt[nt] = *(const bf16x8*)(wbase + nt * 16 * ldw + k0 + 32);
        }
#pragma unroll
        for (int i = 0; i < 4; ++i) {
            bf16x8 af = *(const bf16x8*)(src + (i * 16 + l15) * sstr + k0 + quad * 8);
#pragma unroll
            for (int nt = 0; nt < NT; ++nt)
                acc[i][nt] = __builtin_amdgcn_mfma_f32_16x16x32_bf16(af, bcur[nt], acc[i][nt], 0, 0, 0);
        }
        if (k0 + 32 < K) {
#pragma unroll
            for (int nt = 0; nt < NT; ++nt) bcur[nt] = bnxt[nt];
        }
    }
}

template <int NT>
__device__ __forceinline__ void store_tiles(
    f32x4 (&acc)[4][NT], unsigned short* __restrict__ dst,
    int col0, const float* __restrict__ bias, int Nreal, int act, int ln)
{
    int quad = ln >> 4, l15 = ln & 15;
#pragma unroll
    for (int nt = 0; nt < NT; ++nt) {
        int col = col0 + nt * 16 + l15;
        float bv = (bias && col < Nreal) ? bias[col] : 0.f;
#pragma unroll
        for (int i = 0; i < 4; ++i) {
#pragma unroll
            for (int r = 0; r < 4; ++r) {
                int row = i * 16 + quad * 4 + r;
                float v = acc[i][nt][r] + bv;
                if (act) v = selu_f(v);
                if (col >= Nreal) v = 0.f;
                dst[row * ASTR + col] = f2bf(v);
            }
        }
    }
}

// ---------------------------------------------------------------------------
// pre_mega: encode -> (h,x1) -> c12+norms -> x2 -> x3 -> xw -> xwTb(transposed)
// 256 blocks x 512 thr; block = 64 rows.
// ---------------------------------------------------------------------------
__global__ __launch_bounds__(512) void pre_mega(
    const float* __restrict__ X,
    const unsigned short* __restrict__ WTd, const float* __restrict__ bcat,
    const unsigned short* __restrict__ WTc12, const float* __restrict__ bc12,
    const unsigned short* __restrict__ WTin2, const float* __restrict__ b_in2,
    const unsigned short* __restrict__ WTin3, const float* __restrict__ b_in3,
    const unsigned short* __restrict__ WTconv,
    unsigned short* __restrict__ c1b, unsigned short* __restrict__ c2b,
    float* __restrict__ n1, float* __restrict__ n2,
    unsigned short* __restrict__ xwTb)
{
    __shared__ unsigned short encs[64 * 32];
    __shared__ unsigned short bufA[64 * ASTR];
    __shared__ unsigned short bufB[64 * ASTR];
    __shared__ float c12s[64 * 68];

    int tid = threadIdx.x, wv = tid >> 6, ln = tid & 63;
    int quad = ln >> 4, l15 = ln & 15;
    int row0 = blockIdx.x * 64;

    // encode into LDS
#pragma unroll
    for (int p = 0; p < 4; ++p) {
        int idx = p * 512 + tid;
        int row = idx >> 5, col = idx & 31;
        float v = 0.f;
        if (col < 11) {
            int id = (int)X[(size_t)(row0 + row) * 15];
            v = (id == col) ? SELU_SCALE : 0.f;
        } else if (col < 25) {
            v = selu_f(X[(size_t)(row0 + row) * 15 + 1 + (col - 11)]);
        }
        encs[row * 32 + col] = f2bf(v);
    }
    __syncthreads();

    // h -> bufA (ph=0), x1 -> bufB (ph=1); K=32
#pragma unroll
    for (int ph = 0; ph < 2; ++ph) {
        f32x4 acc[4][2]; zero_acc<2>(acc);
        compute_tiles<2, 32>(acc, encs, 32, WTd + (size_t)ph * 256 * 32, 32, wv * 32, ln);
        store_tiles<2>(acc, ph ? bufB : bufA, wv * 32, bcat + ph * 256, 256, 1, ln);
    }
    __syncthreads();

    // c12 = h @ Wc12 + b (fp32 LDS), waves 0,1
    if (wv < 2) {
        f32x4 acc[4][2]; zero_acc<2>(acc);
        compute_tiles<2, 256>(acc, bufA, ASTR, WTc12, 256, wv * 32, ln);
#pragma unroll
        for (int nt = 0; nt < 2; ++nt) {
            int col = wv * 32 + nt * 16 + l15;
            float bv = bc12[col];
#pragma unroll
            for (int i = 0; i < 4; ++i)
#pragma unroll
                for (int r = 0; r < 4; ++r)
                    c12s[(i * 16 + quad * 4 + r) * 68 + col] = acc[i][nt][r] + bv;
        }
    }
    __syncthreads();

    // norms + bf16 c1/c2 (one thread per row) — overlaps x2 compute
    if (tid < 64) {
        int grow = row0 + tid;
        const float* p = &c12s[tid * 68];
        float s1 = 0.f, s2 = 0.f;
        unsigned int o1[16], o2[16];
#pragma unroll
        for (int k = 0; k < 32; k += 2) {
            float a0 = p[k], a1 = p[k + 1];
            s1 += a0 * a0 + a1 * a1;
            o1[k >> 1] = (unsigned)f2bf(a0) | ((unsigned)f2bf(a1) << 16);
            float b0 = p[32 + k], b1 = p[33 + k];
            s2 += b0 * b0 + b1 * b1;
            o2[k >> 1] = (unsigned)f2bf(b0) | ((unsigned)f2bf(b1) << 16);
        }
        uint4* d1 = (uint4*)(c1b + (size_t)grow * 32);
        uint4* d2 = (uint4*)(c2b + (size_t)grow * 32);
#pragma unroll
        for (int j = 0; j < 4; ++j) {
            d1[j] = make_uint4(o1[4 * j], o1[4 * j + 1], o1[4 * j + 2], o1[4 * j + 3]);
            d2[j] = make_uint4(o2[4 * j], o2[4 * j + 1], o2[4 * j + 2], o2[4 * j + 3]);
        }
        n1[grow] = s1;
        n2[grow] = s2;
    }

    // x2 = selu(x1 @ Win2 + b): bufB -> bufA
    {
        f32x4 acc[4][2]; zero_acc<2>(acc);
        compute_tiles<2, 256>(acc, bufB, ASTR, WTin2, 256, wv * 32, ln);
        store_tiles<2>(acc, bufA, wv * 32, b_in2, 256, 1, ln);
    }
    __syncthreads();
    // x3: bufA -> bufB
    {
        f32x4 acc[4][2]; zero_acc<2>(acc);
        compute_tiles<2, 256>(acc, bufA, ASTR, WTin3, 256, wv * 32, ln);
        store_tiles<2>(acc, bufB, wv * 32, b_in3, 256, 1, ln);
    }
    __syncthreads();
    // xw = x3 @ Wconv (no bias/act): bufB -> bufA
    {
        f32x4 acc[4][2]; zero_acc<2>(acc);
        compute_tiles<2, 256>(acc, bufB, ASTR, WTconv, 256, wv * 32, ln);
        store_tiles<2>(acc, bufA, wv * 32, nullptr, 256, 0, ln);
    }
    __syncthreads();

    // transpose-write xwTb [b][chunk][256 h][32 m]
    int b = row0 >> 12;
    int c0 = (row0 & 4095) >> 5;
#pragma unroll
    for (int p = 0; p < 4; ++p) {
        int idx = p * 512 + tid;          // 0..2047
        int h = idx >> 3, mg = idx & 7;
        unsigned int w[4];
#pragma unroll
        for (int j = 0; j < 4; ++j) {
            unsigned int lo = bufA[(mg * 8 + 2 * j) * ASTR + h];
            unsigned int hi = bufA[(mg * 8 + 2 * j + 1) * ASTR + h];
            w[j] = lo | (hi << 16);
        }
        *(uint4*)(xwTb + ((size_t)((b * 128 + c0 + (mg >> 2)) * 256 + h) * 32) + (mg & 3) * 8) =
            make_uint4(w[0], w[1], w[2], w[3]);
    }
}

// ---------------------------------------------------------------------------
// fused adjacency conv: 512 blocks x 256 thr (4 waves), tile 32i x 256h,
// stream m in 64-chunks; double-buffered wls, ONE barrier per chunk.
// ---------------------------------------------------------------------------
__global__ __launch_bounds__(256) void adj_conv_mfma(
    const unsigned short* __restrict__ c1b, const unsigned short* __restrict__ c2b,
    const float* __restrict__ n1, const float* __restrict__ n2,
    const unsigned short* __restrict__ xwTb, const float* __restrict__ bconv,
    unsigned short* __restrict__ xc)
{
    __shared__ unsigned short wls[2][32][72];

    int tid = threadIdx.x, wv = tid >> 6, ln = tid & 63, quad = ln >> 4, l15 = ln & 15;
    int blk = blockIdx.x;
    int b = (blk >> 1) & 3;                      // XCD pair -> batch
    int iidx = ((blk >> 3) << 1) | (blk & 1);    // 0..127
    int i0 = iidx * 32;
    size_t base = (size_t)b * NSEQ;

    int it = wv & 1;                 // dot i-tile
    int mtb = (wv >> 1) << 1;        // dot m-tiles mtb, mtb+1

    bf16x8 c1f = *(const bf16x8*)(c1b + (base + i0 + it * 16 + l15) * 32 + quad * 8);
    float4 n1v = *(const float4*)(n1 + base + i0 + it * 16 + quad * 4);
    const unsigned short* xwb = xwTb + (size_t)b * 128 * 256 * 32;

    f32x4 acc[2][4];
#pragma unroll
    for (int i = 0; i < 2; ++i)
#pragma unroll
        for (int j = 0; j < 4; ++j) acc[i][j] = (f32x4){0.f, 0.f, 0.f, 0.f};

    // prefetch chunk 0
    bf16x8 c2f[2]; float nn2[2];
    bf16x8 bfc[4][2];
#pragma unroll
    for (int t = 0; t < 2; ++t) {
        c2f[t] = *(const bf16x8*)(c2b + (base + (mtb + t) * 16 + l15) * 32 + quad * 8);
        nn2[t] = n2[base + (mtb + t) * 16 + l15];
    }
#pragma unroll
    for (int ht = 0; ht < 4; ++ht)
#pragma unroll
        for (int ks = 0; ks < 2; ++ks)
            bfc[ht][ks] = *(const bf16x8*)(xwb +
                ((size_t)ks * 256 + wv * 64 + ht * 16 + l15) * 32 + quad * 8);

#pragma unroll 2
    for (int itr = 0; itr < 64; ++itr) {
        int p = itr & 1;
        // dot phase: 2 MFMAs + exp -> wls[p]
#pragma unroll
        for (int t = 0; t < 2; ++t) {
            f32x4 dotv = (f32x4){0.f, 0.f, 0.f, 0.f};
            dotv = __builtin_amdgcn_mfma_f32_16x16x32_bf16(c1f, c2f[t], dotv, 0, 0, 0);
            float s = nn2[t];
#pragma unroll
            for (int r = 0; r < 4; ++r) {
                float D = fmaf(-2.f, dotv[r], n1v[r] + s);
                D = fmaxf(D, 1e-12f);
                wls[p][it * 16 + quad * 4 + r][(mtb + t) * 16 + l15] = t2bf(__expf(-4.f * sqrtf(D)));
            }
        }
        __syncthreads();

        bf16x8 af[2][2];
#pragma unroll
        for (int mi = 0; mi < 2; ++mi)
#pragma unroll
            for (int ks = 0; ks < 2; ++ks)
                af[mi][ks] = *(const bf16x8*)&wls[p][mi * 16 + l15][ks * 32 + quad * 8];

        bf16x8 bfn[4][2];
        if (itr < 63) {
            int m0n = (itr + 1) * 64;
#pragma unroll
            for (int t = 0; t < 2; ++t) {
                c2f[t] = *(const bf16x8*)(c2b + (base + m0n + (mtb + t) * 16 + l15) * 32 + quad * 8);
                nn2[t] = n2[base + m0n + (mtb + t) * 16 + l15];
            }
#pragma unroll
            for (int ht = 0; ht < 4; ++ht)
#pragma unroll
                for (int ks = 0; ks < 2; ++ks)
                    bfn[ht][ks] = *(const bf16x8*)(xwb +
                        ((size_t)((itr + 1) * 2 + ks) * 256 + wv * 64 + ht * 16 + l15) * 32 + quad * 8);
        }

#pragma unroll
        for (int mi = 0; mi < 2; ++mi)
#pragma unroll
            for (int ht = 0; ht < 4; ++ht)
#pragma unroll
                for (int ks = 0; ks < 2; ++ks)
                    acc[mi][ht] = __builtin_amdgcn_mfma_f32_16x16x32_bf16(
                        af[mi][ks], bfc[ht][ks], acc[mi][ht], 0, 0, 0);
        if (itr < 63) {
#pragma unroll
            for (int ht = 0; ht < 4; ++ht)
#pragma unroll
                for (int ks = 0; ks < 2; ++ks)
                    bfc[ht][ks] = bfn[ht][ks];
        }
        // no second barrier: next iter writes wls[p^1] only
    }

    // epilogue: + bconv, selu, store bf16 (stride 256)
#pragma unroll
    for (int mi = 0; mi < 2; ++mi) {
#pragma unroll
        for (int ht = 0; ht < 4; ++ht) {
            int h = wv * 64 + ht * 16 + l15;
            float bv = bconv[h];
#pragma unroll
            for (int r = 0; r < 4; ++r) {
                int irow = i0 + mi * 16 + quad * 4 + r;
                xc[(base + irow) * 256 + h] = f2bf(selu_f(acc[mi][ht][r] + bv));
            }
        }
    }
}

// ---------------------------------------------------------------------------
// post_mega: xc -> id1..3 -> logits -> [xc|selu(log)] -> m1..3 -> out
// 256 blocks x 512 thr; block = 64 rows; writes d_out directly.
// ---------------------------------------------------------------------------
__global__ __launch_bounds__(512) void post_mega(
    const float* __restrict__ X, const unsigned short* __restrict__ xc,
    const unsigned short* __restrict__ WTid1, const float* __restrict__ b_id1,
    const unsigned short* __restrict__ WTid2, const float* __restrict__ b_id2,
    const unsigned short* __restrict__ WTid3, const float* __restrict__ b_id3,
    const unsigned short* __restrict__ WToo, const float* __restrict__ boo,
    const unsigned short* __restrict__ WTm1, const float* __restrict__ b_m1,
    const unsigned short* __restrict__ WTm2, const float* __restrict__ b_m2,
    const unsigned short* __restrict__ WTm3, const float* __restrict__ b_m3,
    const unsigned short* __restrict__ WTom, const float* __restrict__ b_om,
    float* __restrict__ out)
{
    __shared__ unsigned short xcs[64 * ASTR];
    __shared__ unsigned short bufA[64 * ASTR];
    __shared__ unsigned short bufB[64 * ASTR];
    __shared__ float lgs[64 * 16];

    int tid = threadIdx.x, wv = tid >> 6, ln = tid & 63;
    int quad = ln >> 4, l15 = ln & 15;
    int row0 = blockIdx.x * 64;

    // load xc tile
#pragma unroll
    for (int p = 0; p < 4; ++p) {
        int idx = p * 512 + tid;
        int row = idx >> 5, c8 = (idx & 31) * 8;
        *(uint4*)&xcs[row * ASTR + c8] = *(const uint4*)(xc + (size_t)(row0 + row) * 256 + c8);
    }
    // zero pad cols 256..295 of xcs and bufB (K=288 layers)
#pragma unroll
    for (int p = 0; p < 5; ++p) {
        int idx = p * 512 + tid;      // 2560
        int row = idx / 40, c = 256 + idx - row * 40;
        xcs[row * ASTR + c] = 0;
        bufB[row * ASTR + c] = 0;
    }
    __syncthreads();

    // a1: xcs -> bufA
    {
        f32x4 acc[4][2]; zero_acc<2>(acc);
        compute_tiles<2, 256>(acc, xcs, ASTR, WTid1, 256, wv * 32, ln);
        store_tiles<2>(acc, bufA, wv * 32, b_id1, 256, 1, ln);
    }
    __syncthreads();
    // a2: bufA -> bufB
    {
        f32x4 acc[4][2]; zero_acc<2>(acc);
        compute_tiles<2, 256>(acc, bufA, ASTR, WTid2, 256, wv * 32, ln);
        store_tiles<2>(acc, bufB, wv * 32, b_id2, 256, 1, ln);
    }
    __syncthreads();
    // a3: bufB -> bufA
    {
        f32x4 acc[4][2]; zero_acc<2>(acc);
        compute_tiles<2, 256>(acc, bufB, ASTR, WTid3, 256, wv * 32, ln);
        store_tiles<2>(acc, bufA, wv * 32, b_id3, 256, 1, ln);
    }
    __syncthreads();
    // logits (cols 0..15: 0..7 oid, 8..9 och): wave 0 only
    if (wv == 0) {
        f32x4 acc[4][1]; zero_acc<1>(acc);
        compute_tiles<1, 256>(acc, bufA, ASTR, WToo, 256, 0, ln);
        float bv = boo[l15];
#pragma unroll
        for (int i = 0; i < 4; ++i)
#pragma unroll
            for (int r = 0; r < 4; ++r)
                lgs[(i * 16 + quad * 4 + r) * 16 + l15] = acc[i][0][r] + bv;
    }
    __syncthreads();
    // emit id+charge outputs; append selu(logits) to xcs cols 256..263
    if (tid < 64) {
        float* op = out + (size_t)(row0 + tid) * 13;
#pragma unroll
        for (int c = 0; c < 8; ++c) {
            float lg = lgs[tid * 16 + c];
            op[c] = lg;
            xcs[tid * ASTR + 256 + c] = f2bf(selu_f(lg));
        }
        op[11] = lgs[tid * 16 + 8];
        op[12] = lgs[tid * 16 + 9];
    }
    __syncthreads();
    // bb1 = selu(xb @ Wm1 + b), K=288, N=264: xcs -> bufB (+extra tile wave 0)
    {
        f32x4 acc[4][2]; zero_acc<2>(acc);
        compute_tiles<2, 288>(acc, xcs, ASTR, WTm1, 288, wv * 32, ln);
        store_tiles<2>(acc, bufB, wv * 32, b_m1, 264, 1, ln);
        if (wv == 0) {
            f32x4 acx[4][1]; zero_acc<1>(acx);
            compute_tiles<1, 288>(acx, xcs, ASTR, WTm1, 288, 256, ln);
            store_tiles<1>(acx, bufB, 256, b_m1, 264, 1, ln);
        }
    }
    __syncthreads();
    // bb2: bufB (K=288) -> bufA
    {
        f32x4 acc[4][2]; zero_acc<2>(acc);
        compute_tiles<2, 288>(acc, bufB, ASTR, WTm2, 288, wv * 32, ln);
        store_tiles<2>(acc, bufA, wv * 32, b_m2, 256, 1, ln);
    }
    __syncthreads();
    // bb3: bufA (K=256) -> bufB
    {
        f32x4 acc[4][2]; zero_acc<2>(acc);
        compute_tiles<2, 256>(acc, bufA, ASTR, WTm3, 256, wv * 32, ln);
        store_tiles<2>(acc, bufB, wv * 32, b_m3, 256, 1, ln);
    }
    __syncthreads();
    // om + momentum assembly: wave 0
    if (wv == 0) {
        f32x4 acc[4][1]; zero_acc<1>(acc);
        compute_tiles<1, 256>(acc, bufB, ASTR, WTom, 256, 0, ln);
        if (l15 < 3) {
            float bv = b_om[l15];
#pragma unroll
            for (int i = 0; i < 4; ++i)
#pragma unroll
                for (int r = 0; r < 4; ++r) {
                    int grow = row0 + i * 16 + quad * 4 + r;
                    out[(size_t)grow * 13 + 8 + l15] =
                        X[(size_t)grow * 15 + 2 + l15] + acc[i][0][r] + bv;
                }
        }
    }
}

extern "C" void kernel_launch(void* const* d_in, const int* in_sizes, int n_in,
                              void* d_out, int out_size, void* d_ws, size_t ws_size,
                              hipStream_t stream) {
    (void)in_sizes; (void)n_in; (void)out_size; (void)ws_size;

    const float* X = (const float*)d_in[0];
    const float* W_dc1 = (const float*)d_in[1];  const float* b_dc1 = (const float*)d_in[2];
    const float* W_dc21 = (const float*)d_in[3]; const float* b_dc21 = (const float*)d_in[4];
    const float* W_dc22 = (const float*)d_in[5]; const float* b_dc22 = (const float*)d_in[6];
    const float* W_in1 = (const float*)d_in[7];  const float* b_in1 = (const float*)d_in[8];
    const float* W_in2 = (const float*)d_in[9];  const float* b_in2 = (const float*)d_in[10];
    const float* W_in3 = (const float*)d_in[11]; const float* b_in3 = (const float*)d_in[12];
    const float* W_conv = (const float*)d_in[13]; const float* b_conv = (const float*)d_in[14];
    const float* W_id1 = (const float*)d_in[15]; const float* b_id1 = (const float*)d_in[16];
    const float* W_id2 = (const float*)d_in[17]; const float* b_id2 = (const float*)d_in[18];
    const float* W_id3 = (const float*)d_in[19]; const float* b_id3 = (const float*)d_in[20];
    const float* W_oid = (const float*)d_in[21]; const float* b_oid = (const float*)d_in[22];
    const float* W_och = (const float*)d_in[23]; const float* b_och = (const float*)d_in[24];
    const float* W_m1 = (const float*)d_in[25];  const float* b_m1 = (const float*)d_in[26];
    const float* W_m2 = (const float*)d_in[27];  const float* b_m2 = (const float*)d_in[28];
    const float* W_m3 = (const float*)d_in[29];  const float* b_m3 = (const float*)d_in[30];
    const float* W_om = (const float*)d_in[31];  const float* b_om = (const float*)d_in[32];

    const size_t M = MROWS;
    char* pw = (char*)d_ws;
    auto alloc = [&](size_t bytes) -> void* {
        void* r = (void*)pw;
        pw += (bytes + 255) & ~(size_t)255;
        return r;
    };
    unsigned short* c1b = (unsigned short*)alloc(M * 32 * 2);
    unsigned short* c2b = (unsigned short*)alloc(M * 32 * 2);
    float* n1 = (float*)alloc(M * 4);
    float* n2 = (float*)alloc(M * 4);
    unsigned short* xwTb = (unsigned short*)alloc((size_t)4 * 128 * 256 * 32 * 2);
    unsigned short* xcb = (unsigned short*)alloc(M * 256 * 2);
    unsigned short* WTd = (unsigned short*)alloc(512 * 32 * 2);
    unsigned short* WTc12 = (unsigned short*)alloc(64 * 256 * 2);
    unsigned short* WTin2 = (unsigned short*)alloc(256 * 256 * 2);
    unsigned short* WTin3 = (unsigned short*)alloc(256 * 256 * 2);
    unsigned short* WTconv = (unsigned short*)alloc(256 * 256 * 2);
    unsigned short* WTid1 = (unsigned short*)alloc(256 * 256 * 2);
    unsigned short* WTid2 = (unsigned short*)alloc(256 * 256 * 2);
    unsigned short* WTid3 = (unsigned short*)alloc(256 * 256 * 2);
    unsigned short* WTm3 = (unsigned short*)alloc(256 * 256 * 2);
    unsigned short* WToo = (unsigned short*)alloc(64 * 256 * 2);
    unsigned short* WTm1 = (unsigned short*)alloc(320 * 288 * 2);
    unsigned short* WTm2 = (unsigned short*)alloc(256 * 288 * 2);
    unsigned short* WTom = (unsigned short*)alloc(64 * 256 * 2);
    float* bc12 = (float*)alloc(64 * 4);
    float* boo = (float*)alloc(64 * 4);
    float* bcat = (float*)alloc(512 * 4);

    PrepArgs pa;
    pa.e[0]  = {W_dc1,  WTd,               256, 25,  256, 32};
    pa.e[1]  = {W_in1,  WTd + 256 * 32,    256, 25,  256, 32};
    pa.e[2]  = {W_dc21, WTc12,             32,  256, 32,  256};
    pa.e[3]  = {W_dc22, WTc12 + 32 * 256,  32,  256, 32,  256};
    pa.e[4]  = {W_in2,  WTin2,             256, 256, 256, 256};
    pa.e[5]  = {W_in3,  WTin3,             256, 256, 256, 256};
    pa.e[6]  = {W_conv, WTconv,            256, 256, 256, 256};
    pa.e[7]  = {W_id1,  WTid1,             256, 256, 256, 256};
    pa.e[8]  = {W_id2,  WTid2,             256, 256, 256, 256};
    pa.e[9]  = {W_id3,  WTid3,             256, 256, 256, 256};
    pa.e[10] = {W_m3,   WTm3,              256, 256, 256, 256};
    pa.e[11] = {W_oid,  WToo,              8,   256, 8,   256};
    pa.e[12] = {W_och,  WToo + 8 * 256,    2,   256, 56,  256};
    pa.e[13] = {W_m1,   WTm1,              264, 264, 320, 288};
    pa.e[14] = {W_m2,   WTm2,              256, 264, 256, 288};
    pa.e[15] = {W_om,   WTom,              3,   256, 64,  256};
    pa.b21 = b_dc21; pa.b22 = b_dc22; pa.boid = b_oid; pa.boch = b_och;
    pa.bdc1 = b_dc1; pa.bin1 = b_in1;
    pa.bc12 = bc12; pa.boo = boo; pa.bcat = bcat;
    prep_kernel<<<dim3(360, 17), 256, 0, stream>>>(pa);

    pre_mega<<<dim3(256), 512, 0, stream>>>(X, WTd, bcat, WTc12, bc12,
                                            WTin2, b_in2, WTin3, b_in3, WTconv,
                                            c1b, c2b, n1, n2, xwTb);

    adj_conv_mfma<<<dim3(512), 256, 0, stream>>>(c1b, c2b, n1, n2, xwTb, b_conv, xcb);

    post_mega<<<dim3(256), 512, 0, stream>>>(X, xcb,
                                             WTid1, b_id1, WTid2, b_id2, WTid3, b_id3,
                                             WToo, boo, WTm1, b_m1, WTm2, b_m2,
                                             WTm3, b_m3, WTom, b_om, (float*)d_out);
}